// Round 7
// baseline (1124.245 us; speedup 1.0000x reference)
//
#include <hip/hip_runtime.h>
#include <math.h>

#define GG 512
#define TT 25
#define PP 10
#define MM 5
#define EE 32
#define HID 32
#define HH 128
#define NEDGE 40
#define NGRAPH (GG*TT)          // 12800
#define NTOT (GG*TT*PP)         // 128000

typedef __attribute__((ext_vector_type(8))) short short8v;
typedef __attribute__((ext_vector_type(4))) short short4v;
typedef __attribute__((ext_vector_type(4))) float f32x4;

// A-panel LDS index: [s][ki<6][mt<2][lane<64][e<8] (shorts)
#define AIDX(s,ki,mt,l) (((((s)*6+(ki))*2+(mt))*64+(l))*8)
#define WB_PER_T 196608   // 2*6*32*64*8

__device__ __forceinline__ unsigned short f2bf(float x){
    unsigned u = __float_as_uint(x);
    u += 0x7fffu + ((u >> 16) & 1u);
    return (unsigned short)(u >> 16);
}
__device__ __forceinline__ float bf2f(unsigned short s){
    return __uint_as_float(((unsigned)s) << 16);
}
__device__ __forceinline__ float sigm(float x){ return 1.f/(1.f+__expf(-x)); }
__device__ __forceinline__ float tanh_fast(float x){
    float ax = fabsf(x);
    float e  = __expf(-2.f*ax);
    float t  = (1.f-e)/(1.f+e);
    return copysignf(t, x);
}

// ---------------------------------------------------------------------------
// Prep: build MFMA-fragment weight tensor wB[t][s][ki][nt][lane][e] (bf16 bits)
// ---------------------------------------------------------------------------
__global__ void prep_kernel(const float* __restrict__ W_ih, const float* __restrict__ W_hh,
                            const float* __restrict__ b_ih, const float* __restrict__ b_hh,
                            short* __restrict__ wB, float* __restrict__ wadd,
                            float* __restrict__ bsum)
{
    const int NW = TT*WB_PER_T;          // 4,915,200
    const int NA = TT*2*512;             // 25,600
    const int NB = TT*512;               // 12,800
    for (int idx = blockIdx.x*blockDim.x + threadIdx.x; idx < NW+NA+NB;
         idx += gridDim.x*blockDim.x) {
        if (idx < NW) {
            int e  = idx & 7;
            int l  = (idx >> 3) & 63;
            int nt = (idx >> 9) & 31;
            int rest = idx >> 14;        // (t*2+s)*6 + ki
            int ki = rest % 6; rest /= 6;
            int s  = rest & 1;
            int t  = rest >> 1;
            int k  = ki*32 + (l >> 4)*8 + e;
            int n  = nt*16 + (l & 15);
            float wv = (k < 128) ? W_hh[(size_t)(t*512 + n)*128 + k]
                                 : W_ih[(size_t)(t*512 + n)*66 + (k - 128)];
            unsigned short hi = f2bf(wv);
            unsigned short outv = (s == 0) ? hi : f2bf(wv - bf2f(hi));
            wB[idx] = (short)outv;
        } else if (idx < NW + NA) {
            int i2 = idx - NW;
            int t = i2 / 1024, r = i2 % 1024;
            int cc = r >> 9, n = r & 511;
            wadd[i2] = W_ih[(size_t)(t*512 + n)*66 + 64 + cc];
        } else {
            int i3 = idx - NW - NA;
            bsum[i3] = b_ih[i3] + b_hh[i3];
        }
    }
}

// ---------------------------------------------------------------------------
// Graph kernel v4: one 64-thread (1-wave) block per vote graph.
// Lane = (sign, g4 n-split {3,3,2,2}, l8 -> 4 cols). Full-K GEMM per lane
// (no k-split reduce); bucket Y stays in registers; Adj-apply gathers other
// groups' Y via shfl_xor((sg^g4)<<3) -- no LDS round-trip, no barriers.
// ---------------------------------------------------------------------------
__global__ __launch_bounds__(64) void graph_kernel(
    const float* __restrict__ x0,
    const float* __restrict__ Wb_pos, const float* __restrict__ bb_pos,
    const float* __restrict__ Wb_neg, const float* __restrict__ bb_neg,
    const float* __restrict__ Wd_pos, const float* __restrict__ bd_pos,
    const float* __restrict__ Wd_neg, const float* __restrict__ bd_neg,
    const int* __restrict__ pos_src, const int* __restrict__ pos_dst,
    const int* __restrict__ neg_src, const int* __restrict__ neg_dst,
    float* __restrict__ emb)
{
    __shared__ float Sx[10][64];        // 2560 B
    __shared__ float Sh[2][10][32];     // 2560 B
    __shared__ float Adj[4][10][10];    // 1600 B
    __shared__ float Cm[2][10][10];     //  800 B
    __shared__ float Scnt[4][10];       //  160 B
    __shared__ int   Ses[4][40];        //  640 B   total 8320 B

    const int gid = blockIdx.x;
    const int nb  = gid * PP;
    const int tid = threadIdx.x;

    for (int i = tid; i < 160; i += 64)
        ((float4*)Sx)[i] = ((const float4*)x0)[nb*16 + i];
    for (int i = tid; i < 160; i += 64) {
        int b = i / 40, e = i % 40;
        const int* p = (b==0)?pos_src:(b==1)?pos_dst:(b==2)?neg_src:neg_dst;
        ((int*)Ses)[i] = p[gid*40 + e];
    }
    for (int i = tid; i < 200; i += 64) ((float*)Cm)[i] = 0.f;
    __syncthreads();
    if (tid < 40) {
        atomicAdd(&Cm[0][Ses[0][tid]][Ses[1][tid]], 1.f);
        atomicAdd(&Cm[1][Ses[2][tid]][Ses[3][tid]], 1.f);
    }
    __syncthreads();
    if (tid < 40) {
        int b = tid / 10, n = tid % 10;
        int si = b >> 1, isCol = b & 1;
        float s = 0.f;
        for (int m = 0; m < 10; ++m)
            s += isCol ? Cm[si][m][n] : Cm[si][n][m];
        Scnt[b][n] = fmaxf(s, 1.f);
    }
    __syncthreads();
    for (int i = tid; i < 400; i += 64) {
        int a = i / 100, r = i % 100, n = r / 10, m = r % 10;
        int si = a >> 1, isOut = a & 1;
        float cv = isOut ? Cm[si][m][n] : Cm[si][n][m];
        Adj[a][n][m] = cv / Scnt[si*2 + isOut][n];
    }
    __syncthreads();

    const int sign = tid >> 5;
    const int g4   = (tid >> 3) & 3;
    const int l8   = tid & 7;
    const int c0   = 4*l8;
    const int nb0  = (g4 < 2) ? 3*g4 : 2*g4 + 2;   // 0,3,6,8
    const int nc   = (g4 < 2) ? 3 : 2;

    // Adj-apply: acc2 += AdjA @ Y, Y gathered cross-group via shfl_xor.
    // (defined as a lambda-like macro to keep everything statically indexed)
#define ADJ_APPLY(Yv, AdjA)                                                  \
    {                                                                        \
        _Pragma("unroll")                                                    \
        for (int sg = 0; sg < 4; ++sg) {                                     \
            const int snb  = (sg < 2) ? 3*sg : 2*sg + 2;                     \
            const int scnt = (sg < 2) ? 3 : 2;                               \
            const int xm   = (sg ^ g4) << 3;                                 \
            _Pragma("unroll")                                                \
            for (int j2 = 0; j2 < 3; ++j2) {                                 \
                if (j2 < scnt) {                                             \
                    f32x4 yv;                                                \
                    _Pragma("unroll")                                        \
                    for (int q = 0; q < 4; ++q)                              \
                        yv[q] = __shfl_xor(Yv[j2][q], xm);                   \
                    const int m = snb + j2;                                  \
                    _Pragma("unroll")                                        \
                    for (int j = 0; j < 3; ++j)                              \
                        if (j < nc) acc2[j] += (AdjA)[nb0+j][m] * yv;        \
                }                                                            \
            }                                                                \
        }                                                                    \
    }

    // =================== base layer ===================
    {
        const float* Wb = sign ? Wb_neg : Wb_pos;
        f32x4 Ym[3] = {}, Sf[3] = {};
        for (int kb = 0; kb < 16; ++kb) {
            f32x4 wm[4], wsf[4];
#pragma unroll
            for (int kk = 0; kk < 4; ++kk) {
                wm[kk]  = *(const f32x4*)(Wb + (4*kb+kk)*32 + c0);
                wsf[kk] = *(const f32x4*)(Wb + (64+4*kb+kk)*32 + c0);
            }
#pragma unroll
            for (int j = 0; j < 3; ++j) {
                if (j < nc) {
                    f32x4 xv = *(const f32x4*)&Sx[nb0+j][4*kb];
#pragma unroll
                    for (int kk = 0; kk < 4; ++kk) {
                        Ym[j] += xv[kk]*wm[kk];
                        Sf[j] += xv[kk]*wsf[kk];
                    }
                }
            }
        }
        f32x4 acc2[3];
        {
            const float* bb = sign ? bb_neg : bb_pos;
            f32x4 b4 = *(const f32x4*)(bb + c0);
#pragma unroll
            for (int j = 0; j < 3; ++j) acc2[j] = Sf[j] + b4;
        }
        ADJ_APPLY(Ym, Adj[2*sign])
        // l2 norm over 32 cols (l8 x 4 in-reg) + write Sh
#pragma unroll
        for (int j = 0; j < 3; ++j) {
            if (j < nc) {
                f32x4 v = acc2[j];
                float s = v[0]*v[0] + v[1]*v[1] + v[2]*v[2] + v[3]*v[3];
                s += __shfl_xor(s,1); s += __shfl_xor(s,2); s += __shfl_xor(s,4);
                float rn = 1.f / fmaxf(sqrtf(s), 1e-12f);
                *(f32x4*)&Sh[sign][nb0+j][c0] = v * rn;
            }
        }
        __syncthreads();
    }

    // =================== two deep layers ===================
    for (int l = 0; l < 2; ++l) {
        const float* Wd = (sign ? Wd_neg : Wd_pos) + l*7168;
        const float* Hs = &Sh[sign][0][0];
        const float* Ho = &Sh[1-sign][0][0];
        f32x4 Y0[3] = {}, Y1[3] = {}, Y2[3] = {}, Y3[3] = {}, Sf[3] = {};

        // Hs pass: W0 -> Y0, W1 -> Y1, W5(self) -> Sf
        for (int kb = 0; kb < 8; ++kb) {
            f32x4 w0[4], w1[4], w5[4];
#pragma unroll
            for (int kk = 0; kk < 4; ++kk) {
                w0[kk] = *(const f32x4*)(Wd + (4*kb+kk)*32 + c0);
                w1[kk] = *(const f32x4*)(Wd + (32+4*kb+kk)*32 + c0);
                w5[kk] = *(const f32x4*)(Wd + (160+4*kb+kk)*32 + c0);
            }
#pragma unroll
            for (int j = 0; j < 3; ++j) {
                if (j < nc) {
                    f32x4 hv = *(const f32x4*)(Hs + (nb0+j)*32 + 4*kb);
#pragma unroll
                    for (int kk = 0; kk < 4; ++kk) {
                        Y0[j] += hv[kk]*w0[kk];
                        Y1[j] += hv[kk]*w1[kk];
                        Sf[j] += hv[kk]*w5[kk];
                    }
                }
            }
        }
        // Ho pass: W4 -> Y0, W2 -> Y2, W3 -> Y3, W6(self) -> Sf
        for (int kb = 0; kb < 8; ++kb) {
            f32x4 w4[4], w2[4], w3[4], w6[4];
#pragma unroll
            for (int kk = 0; kk < 4; ++kk) {
                w4[kk] = *(const f32x4*)(Wd + (128+4*kb+kk)*32 + c0);
                w2[kk] = *(const f32x4*)(Wd + (64+4*kb+kk)*32 + c0);
                w3[kk] = *(const f32x4*)(Wd + (96+4*kb+kk)*32 + c0);
                w6[kk] = *(const f32x4*)(Wd + (192+4*kb+kk)*32 + c0);
            }
#pragma unroll
            for (int j = 0; j < 3; ++j) {
                if (j < nc) {
                    f32x4 hv = *(const f32x4*)(Ho + (nb0+j)*32 + 4*kb);
#pragma unroll
                    for (int kk = 0; kk < 4; ++kk) {
                        Y0[j] += hv[kk]*w4[kk];
                        Y2[j] += hv[kk]*w2[kk];
                        Y3[j] += hv[kk]*w3[kk];
                        Sf[j] += hv[kk]*w6[kk];
                    }
                }
            }
        }
        f32x4 acc2[3];
        {
            const float* bd = (sign ? bd_neg : bd_pos) + l*32;
            f32x4 b4 = *(const f32x4*)(bd + c0);
#pragma unroll
            for (int j = 0; j < 3; ++j) acc2[j] = Sf[j] + b4;
        }
        ADJ_APPLY(Y0, Adj[2*sign])
        ADJ_APPLY(Y1, Adj[2*sign+1])
        ADJ_APPLY(Y2, Adj[2-2*sign])
        ADJ_APPLY(Y3, Adj[3-2*sign])
        __syncthreads();   // all Hs/Ho reads of this layer retired (1-wave: ordering fence)
#pragma unroll
        for (int j = 0; j < 3; ++j) {
            if (j < nc) {
                f32x4 v = acc2[j];
                float s = v[0]*v[0] + v[1]*v[1] + v[2]*v[2] + v[3]*v[3];
                s += __shfl_xor(s,1); s += __shfl_xor(s,2); s += __shfl_xor(s,4);
                float rn = 1.f / fmaxf(sqrtf(s), 1e-12f);
                v = v * rn;
                if (l == 0) *(f32x4*)&Sh[sign][nb0+j][c0] = v;
                else        *(f32x4*)&emb[(size_t)(nb + nb0 + j)*64 + sign*32 + c0] = v;
            }
        }
        __syncthreads();
    }
#undef ADJ_APPLY
}

// ---------------------------------------------------------------------------
// Persistent MFMA LSTM (unchanged).
// ---------------------------------------------------------------------------
__global__ __launch_bounds__(512) void lstm_mfma(
    const float* __restrict__ emb, const float* __restrict__ add_info,
    const short* __restrict__ wB, const float* __restrict__ wadd,
    const float* __restrict__ bsum, const float* __restrict__ hx0,
    const float* __restrict__ cx0, float* __restrict__ hbuf)
{
    __shared__ short aP[12288];          // [2][6][2][64][8] bf16 bits, 24.6 KB
    __shared__ float Sadd[2][32][2];
    const int tid = threadIdx.x;
    const int w  = tid >> 6;             // wave 0..7
    const int l  = tid & 63;
    const int li = l & 15;
    const int lk = l >> 4;
    const int R0 = blockIdx.x * 32;

    {
        int row = tid >> 4, j0 = (tid & 15) * 8;
        const float* hp = hx0 + (size_t)(R0 + row)*128 + j0;
        float4 h0 = *(const float4*)hp;
        float4 h1 = *(const float4*)(hp + 4);
        float v[8] = {h0.x,h0.y,h0.z,h0.w,h1.x,h1.y,h1.z,h1.w};
        short8v hi, lo;
#pragma unroll
        for (int e = 0; e < 8; ++e) {
            unsigned short hs = f2bf(v[e]);
            hi[e] = (short)hs;
            lo[e] = (short)f2bf(v[e] - bf2f(hs));
        }
        int mt = row >> 4, ln = (row & 15) + 16*((j0 >> 3) & 3), ki = j0 >> 5;
        *(short8v*)&aP[AIDX(0,ki,mt,ln)] = hi;
        *(short8v*)&aP[AIDX(1,ki,mt,ln)] = lo;
    }
    {
        int row = tid >> 4, d0 = (tid & 15)*4;
        int R = R0 + row, g = R/10, p = R - 10*g;
        float4 f = *(const float4*)&emb[((size_t)(g*TT + 0)*PP + p)*64 + d0];
        int k0 = 128 + d0;
        int mt = row>>4, ln = (row&15) + 16*((k0>>3)&3), ki = k0>>5, e0 = k0&7;
        float v[4] = {f.x,f.y,f.z,f.w};
        short4v hi, lo;
#pragma unroll
        for (int e = 0; e < 4; ++e) {
            unsigned short hs = f2bf(v[e]);
            hi[e] = (short)hs;
            lo[e] = (short)f2bf(v[e] - bf2f(hs));
        }
        *(short4v*)&aP[AIDX(0,ki,mt,ln)+e0] = hi;
        *(short4v*)&aP[AIDX(1,ki,mt,ln)+e0] = lo;
    }
    if (tid < 64) {
        int row = tid >> 1, cc = tid & 1;
        int R = R0 + row, g = R/10, p = R - 10*g;
        Sadd[0][row][cc] = add_info[((size_t)(g*MM + 0)*PP + p)*2 + cc];
    }
    float c[2][4];
#pragma unroll
    for (int mt = 0; mt < 2; ++mt)
#pragma unroll
        for (int r = 0; r < 4; ++r) {
            int row = mt*16 + lk*4 + r;
            c[mt][r] = cx0[(size_t)(R0+row)*128 + 16*w + li];
        }
    __syncthreads();

    for (int t = 0; t < TT; ++t) {
        f32x4 acc[2][4];
#pragma unroll
        for (int g = 0; g < 4; ++g) {
            float bs = bsum[t*512 + 128*g + 16*w + li];
            acc[0][g] = (f32x4){bs,bs,bs,bs};
            acc[1][g] = (f32x4){bs,bs,bs,bs};
        }
        const short* wt = wB + (size_t)t * WB_PER_T;
#pragma unroll 2
        for (int ki = 0; ki < 6; ++ki) {
            short8v ah0 = *(const short8v*)&aP[AIDX(0,ki,0,l)];
            short8v ah1 = *(const short8v*)&aP[AIDX(0,ki,1,l)];
            short8v al0 = *(const short8v*)&aP[AIDX(1,ki,0,l)];
            short8v al1 = *(const short8v*)&aP[AIDX(1,ki,1,l)];
#pragma unroll
            for (int g = 0; g < 4; ++g) {
                int nt = w + 8*g;
                short8v bh = *(const short8v*)(wt + (((size_t)ki*32 + nt)*64 + l)*8);
                short8v bl = *(const short8v*)(wt + (((size_t)(6+ki)*32 + nt)*64 + l)*8);
                acc[0][g] = __builtin_amdgcn_mfma_f32_16x16x32_bf16(ah0, bh, acc[0][g], 0, 0, 0);
                acc[0][g] = __builtin_amdgcn_mfma_f32_16x16x32_bf16(ah0, bl, acc[0][g], 0, 0, 0);
                acc[0][g] = __builtin_amdgcn_mfma_f32_16x16x32_bf16(al0, bh, acc[0][g], 0, 0, 0);
                acc[1][g] = __builtin_amdgcn_mfma_f32_16x16x32_bf16(ah1, bh, acc[1][g], 0, 0, 0);
                acc[1][g] = __builtin_amdgcn_mfma_f32_16x16x32_bf16(ah1, bl, acc[1][g], 0, 0, 0);
                acc[1][g] = __builtin_amdgcn_mfma_f32_16x16x32_bf16(al1, bh, acc[1][g], 0, 0, 0);
            }
        }
        __syncthreads();

        float wa0[4], wa1[4];
#pragma unroll
        for (int g = 0; g < 4; ++g) {
            wa0[g] = wadd[(size_t)(t*2+0)*512 + 128*g + 16*w + li];
            wa1[g] = wadd[(size_t)(t*2+1)*512 + 128*g + 16*w + li];
        }
        const int sb = t & 1;
        const int j  = 16*w + li;
        const int jsh = 16*((j >> 3) & 3);
        const int jki = j >> 5;
        const int je  = j & 7;
#pragma unroll
        for (int mt = 0; mt < 2; ++mt) {
#pragma unroll
            for (int r = 0; r < 4; ++r) {
                int row = mt*16 + lk*4 + r;
                float ad0 = Sadd[sb][row][0], ad1 = Sadd[sb][row][1];
                float v0 = acc[mt][0][r] + ad0*wa0[0] + ad1*wa1[0];
                float v1 = acc[mt][1][r] + ad0*wa0[1] + ad1*wa1[1];
                float v2 = acc[mt][2][r] + ad0*wa0[2] + ad1*wa1[2];
                float v3 = acc[mt][3][r] + ad0*wa0[3] + ad1*wa1[3];
                float iv = sigm(v0);
                float fv = sigm(v1);
                float gv = tanh_fast(v2);
                float ov = sigm(v3);
                float cn = fv*c[mt][r] + iv*gv;
                c[mt][r] = cn;
                float hv = ov*tanh_fast(cn);
                unsigned short hs = f2bf(hv);
                int ln = (row & 15) + jsh;
                aP[AIDX(0, jki, mt, ln) + je] = (short)hs;
                aP[AIDX(1, jki, mt, ln) + je] = (short)f2bf(hv - bf2f(hs));
                if (t == TT-1) hbuf[(size_t)(R0+row)*128 + j] = hv;
            }
        }
        if (t < TT-1) {
            int row = tid >> 4, d0 = (tid & 15)*4;
            int R = R0 + row, g = R/10, p = R - 10*g;
            float4 f = *(const float4*)&emb[((size_t)(g*TT + (t+1))*PP + p)*64 + d0];
            int k0 = 128 + d0;
            int mt = row>>4, ln = (row&15) + 16*((k0>>3)&3), ki = k0>>5, e0 = k0&7;
            float v[4] = {f.x,f.y,f.z,f.w};
            short4v hi, lo;
#pragma unroll
            for (int e = 0; e < 4; ++e) {
                unsigned short hs = f2bf(v[e]);
                hi[e] = (short)hs;
                lo[e] = (short)f2bf(v[e] - bf2f(hs));
            }
            *(short4v*)&aP[AIDX(0,ki,mt,ln)+e0] = hi;
            *(short4v*)&aP[AIDX(1,ki,mt,ln)+e0] = lo;
            if (tid < 64) {
                int rw = tid >> 1, cc = tid & 1;
                int R2 = R0 + rw, g2 = R2/10, p2 = R2 - 10*g2;
                Sadd[sb^1][rw][cc] =
                    add_info[((size_t)(g2*MM + (t+1)/MM)*PP + p2)*2 + cc];
            }
        }
        __syncthreads();
    }
}

// ---------------------------------------------------------------------------
// Final projection: out = h_last @ Wf + bf
// ---------------------------------------------------------------------------
__global__ __launch_bounds__(256) void final_proj(
    const float* __restrict__ hbuf, const float* __restrict__ Wf,
    const float* __restrict__ bf, float* __restrict__ out)
{
    __shared__ float wl[128*32];
    __shared__ float hl[64][128];
    const int tid = threadIdx.x;
    const int row0 = blockIdx.x * 64;
    for (int i = tid; i < 4096; i += 256) wl[i] = Wf[i];
    for (int i = tid; i < 8192; i += 256) hl[i>>7][i&127] = hbuf[row0*128 + i];
    __syncthreads();
    const int e  = tid & 31;
    const int rg = tid >> 5;
    float b = bf[e];
    float acc[8];
#pragma unroll
    for (int r=0;r<8;++r) acc[r] = b;
    for (int k = 0; k < 128; ++k) {
        float ww = wl[k*32 + e];
#pragma unroll
        for (int r=0;r<8;++r) acc[r] += hl[rg*8+r][k]*ww;
    }
#pragma unroll
    for (int r=0;r<8;++r) out[(row0 + rg*8 + r)*32 + e] = acc[r];
}

// ---------------------------------------------------------------------------
extern "C" void kernel_launch(void* const* d_in, const int* in_sizes, int n_in,
                              void* d_out, int out_size, void* d_ws, size_t ws_size,
                              hipStream_t stream)
{
    const float* x0       = (const float*)d_in[0];
    const float* add_info = (const float*)d_in[1];
    const float* Wb_pos   = (const float*)d_in[2];
    const float* bb_pos   = (const float*)d_in[3];
    const float* Wb_neg   = (const float*)d_in[4];
    const float* bb_neg   = (const float*)d_in[5];
    const float* Wd_pos   = (const float*)d_in[6];
    const float* bd_pos   = (const float*)d_in[7];
    const float* Wd_neg   = (const float*)d_in[8];
    const float* bd_neg   = (const float*)d_in[9];
    const float* W_ih     = (const float*)d_in[10];
    const float* W_hh     = (const float*)d_in[11];
    const float* b_ih     = (const float*)d_in[12];
    const float* b_hh     = (const float*)d_in[13];
    const float* hx0      = (const float*)d_in[14];
    const float* cx0      = (const float*)d_in[15];
    const float* Wf       = (const float*)d_in[16];
    const float* bf       = (const float*)d_in[17];
    const int*   pos_src  = (const int*)d_in[18];
    const int*   pos_dst  = (const int*)d_in[19];
    const int*   neg_src  = (const int*)d_in[20];
    const int*   neg_dst  = (const int*)d_in[21];

    float* ws    = (float*)d_ws;
    float* emb   = ws;                        // 8,192,000 f32
    float* hbuf  = emb   + 8192000;           //   655,360 f32
    float* bsumw = hbuf  + 655360;            //    12,800 f32
    float* waddw = bsumw + 12800;             //    25,600 f32
    short* wBw   = (short*)(waddw + 25600);   // 4,915,200 bf16-bits (~45.4 MiB total)

    hipLaunchKernelGGL(prep_kernel, dim3(2048), dim3(256), 0, stream,
                       W_ih, W_hh, b_ih, b_hh, wBw, waddw, bsumw);
    hipLaunchKernelGGL(graph_kernel, dim3(NGRAPH), dim3(64), 0, stream,
                       x0, Wb_pos, bb_pos, Wb_neg, bb_neg,
                       Wd_pos, bd_pos, Wd_neg, bd_neg,
                       pos_src, pos_dst, neg_src, neg_dst, emb);
    hipLaunchKernelGGL(lstm_mfma, dim3(160), dim3(512), 0, stream,
                       emb, add_info, wBw, waddw, bsumw, hx0, cx0, hbuf);
    hipLaunchKernelGGL(final_proj, dim3(80), dim3(256), 0, stream,
                       hbuf, Wf, bf, (float*)d_out);
}

// Round 8
// 783.073 us; speedup vs baseline: 1.4357x; 1.4357x over previous
//
#include <hip/hip_runtime.h>
#include <math.h>

#define GG 512
#define TT 25
#define PP 10
#define MM 5
#define EE 32
#define HID 32
#define HH 128
#define NEDGE 40
#define NGRAPH (GG*TT)          // 12800
#define NTOT (GG*TT*PP)         // 128000

typedef __attribute__((ext_vector_type(8))) short short8v;
typedef __attribute__((ext_vector_type(4))) short short4v;
typedef __attribute__((ext_vector_type(4))) float f32x4;

// A-panel LDS index: [s][ki<6][mt<2][lane<64][e<8] (shorts)
#define AIDX(s,ki,mt,l) (((((s)*6+(ki))*2+(mt))*64+(l))*8)
#define WB_PER_T 196608   // 2*6*32*64*8

__device__ __forceinline__ unsigned short f2bf(float x){
    unsigned u = __float_as_uint(x);
    u += 0x7fffu + ((u >> 16) & 1u);
    return (unsigned short)(u >> 16);
}
__device__ __forceinline__ float bf2f(unsigned short s){
    return __uint_as_float(((unsigned)s) << 16);
}
__device__ __forceinline__ float sigm(float x){ return 1.f/(1.f+__expf(-x)); }
__device__ __forceinline__ float tanh_fast(float x){
    float ax = fabsf(x);
    float e  = __expf(-2.f*ax);
    float t  = (1.f-e)/(1.f+e);
    return copysignf(t, x);
}

// ---------------------------------------------------------------------------
// Prep: build MFMA-fragment weight tensor wB[t][s][ki][nt][lane][e] (bf16 bits)
// ---------------------------------------------------------------------------
__global__ void prep_kernel(const float* __restrict__ W_ih, const float* __restrict__ W_hh,
                            const float* __restrict__ b_ih, const float* __restrict__ b_hh,
                            short* __restrict__ wB, float* __restrict__ wadd,
                            float* __restrict__ bsum)
{
    const int NW = TT*WB_PER_T;          // 4,915,200
    const int NA = TT*2*512;             // 25,600
    const int NB = TT*512;               // 12,800
    for (int idx = blockIdx.x*blockDim.x + threadIdx.x; idx < NW+NA+NB;
         idx += gridDim.x*blockDim.x) {
        if (idx < NW) {
            int e  = idx & 7;
            int l  = (idx >> 3) & 63;
            int nt = (idx >> 9) & 31;
            int rest = idx >> 14;        // (t*2+s)*6 + ki
            int ki = rest % 6; rest /= 6;
            int s  = rest & 1;
            int t  = rest >> 1;
            int k  = ki*32 + (l >> 4)*8 + e;
            int n  = nt*16 + (l & 15);
            float wv = (k < 128) ? W_hh[(size_t)(t*512 + n)*128 + k]
                                 : W_ih[(size_t)(t*512 + n)*66 + (k - 128)];
            unsigned short hi = f2bf(wv);
            unsigned short outv = (s == 0) ? hi : f2bf(wv - bf2f(hi));
            wB[idx] = (short)outv;
        } else if (idx < NW + NA) {
            int i2 = idx - NW;
            int t = i2 / 1024, r = i2 % 1024;
            int cc = r >> 9, n = r & 511;
            wadd[i2] = W_ih[(size_t)(t*512 + n)*66 + 64 + cc];
        } else {
            int i3 = idx - NW - NA;
            bsum[i3] = b_ih[i3] + b_hh[i3];
        }
    }
}

// ---------------------------------------------------------------------------
// Graph kernel v5 = r5 structure + float4 GEMM activation reads + LDS overlay.
// One 64-thread block per (g,t) vote graph; Adj matmuls for all seg_means.
// ---------------------------------------------------------------------------
#define REDUCE1016(acc) \
    _Pragma("unroll") for (int n=0;n<10;++n) \
    _Pragma("unroll") for (int q=0;q<4;++q) { \
        float v = acc[n][q]; v += __shfl_xor(v,8); v += __shfl_xor(v,16); acc[n][q]=v; }

__global__ __launch_bounds__(64) void graph_kernel(
    const float* __restrict__ x0,
    const float* __restrict__ Wb_pos, const float* __restrict__ bb_pos,
    const float* __restrict__ Wb_neg, const float* __restrict__ bb_neg,
    const float* __restrict__ Wd_pos, const float* __restrict__ bd_pos,
    const float* __restrict__ Wd_neg, const float* __restrict__ bd_neg,
    const int* __restrict__ pos_src, const int* __restrict__ pos_dst,
    const int* __restrict__ neg_src, const int* __restrict__ neg_dst,
    float* __restrict__ emb)
{
    __shared__ float Sx[10][64];        // 2560 B
    __shared__ float Su[1920];          // 7680 B: Sm[2][10][64] / Sagg[6][10][32] / (Cm|Ses|Scnt)
    __shared__ float Sh[2][10][32];     // 2560 B
    __shared__ float Adj[4][10][10];    // 1600 B   total 14400 B
    float* CmP   = Su;                  // [2][10][10] = 200 f32
    int*   SesP  = (int*)(Su + 200);    // [4][40]    = 160 i32
    float* ScntP = Su + 360;            // [4][10]    =  40 f32  (all dead after Adj)

    const int gid = blockIdx.x;
    const int nb  = gid * PP;
    const int tid = threadIdx.x;

    for (int i = tid; i < 160; i += 64)
        ((float4*)Sx)[i] = ((const float4*)x0)[nb*16 + i];
    for (int i = tid; i < 160; i += 64) {
        int b = i / 40, e = i % 40;
        const int* p = (b==0)?pos_src:(b==1)?pos_dst:(b==2)?neg_src:neg_dst;
        SesP[i] = p[gid*40 + e];
    }
    if (tid < 40) {
        CmP[tid] = 0.f; CmP[tid+40] = 0.f; CmP[tid+80] = 0.f;
        CmP[tid+120] = 0.f; CmP[tid+160] = 0.f;
    }
    __syncthreads();
    if (tid < 40) {
        atomicAdd(&CmP[SesP[tid]*10       + SesP[40 + tid]],  1.f);
        atomicAdd(&CmP[100 + SesP[80+tid]*10 + SesP[120+tid]], 1.f);
    }
    __syncthreads();
    if (tid < 40) {
        int b = tid / 10, n = tid % 10;
        int si = b >> 1, isCol = b & 1;
        float s = 0.f;
        for (int m = 0; m < 10; ++m)
            s += isCol ? CmP[si*100 + m*10 + n] : CmP[si*100 + n*10 + m];
        ScntP[b*10 + n] = fmaxf(s, 1.f);
    }
    __syncthreads();
    for (int i = tid; i < 400; i += 64) {
        int a = i / 100, r = i % 100, n = r / 10, m = r % 10;
        int si = a >> 1, isOut = a & 1;
        float cv = isOut ? CmP[si*100 + m*10 + n] : CmP[si*100 + n*10 + m];
        Adj[a][n][m] = cv / ScntP[(si*2 + isOut)*10 + n];
    }
    __syncthreads();   // Adj ready; Cm/Ses/Scnt dead -> Su reusable as Sm

    // ---- base means via adjacency matmul: thread owns dim d ----
    {
        const int d = tid;
        float xr[10];
#pragma unroll
        for (int m = 0; m < 10; ++m) xr[m] = Sx[m][d];
        float* Sm = Su;   // [2][10][64]
#pragma unroll
        for (int n = 0; n < 10; ++n) {
            float mp = 0.f, mn2 = 0.f;
#pragma unroll
            for (int m = 0; m < 10; ++m) {
                mp  += Adj[0][n][m] * xr[m];
                mn2 += Adj[2][n][m] * xr[m];
            }
            Sm[(0*10 + n)*64 + d] = mp;
            Sm[(1*10 + n)*64 + d] = mn2;
        }
    }
    __syncthreads();

    const int sign = tid >> 5;
    const int g4   = (tid >> 3) & 3;
    const int l8   = tid & 7;
    const int c0   = 4*l8;
    const int kp   = g4*8;
    const int cv   = tid & 31;

    float acc[10][4];
#pragma unroll
    for (int n=0;n<10;++n) { acc[n][0]=0.f; acc[n][1]=0.f; acc[n][2]=0.f; acc[n][3]=0.f; }

    // ---- base GEMM: feats = [mean_in(64) | x(64)], W (128x32), float4 reads ----
    {
        const float* Wb = sign ? Wb_neg : Wb_pos;
        const float* fb0 = Su + sign*640;
#pragma unroll
        for (int blk = 0; blk < 4; ++blk) {
            const float* bp = ((blk < 2) ? fb0 : &Sx[0][0]) + (blk & 1)*32 + kp;
            const float* wrow = Wb + (blk*32 + kp)*32 + c0;
#pragma unroll
            for (int kb = 0; kb < 2; ++kb) {
                float4 w0 = *(const float4*)(wrow + (4*kb+0)*32);
                float4 w1 = *(const float4*)(wrow + (4*kb+1)*32);
                float4 w2 = *(const float4*)(wrow + (4*kb+2)*32);
                float4 w3 = *(const float4*)(wrow + (4*kb+3)*32);
#pragma unroll
                for (int n = 0; n < 10; ++n) {
                    float4 f = *(const float4*)(bp + n*64 + 4*kb);
                    acc[n][0] += f.x*w0.x + f.y*w1.x + f.z*w2.x + f.w*w3.x;
                    acc[n][1] += f.x*w0.y + f.y*w1.y + f.z*w2.y + f.w*w3.y;
                    acc[n][2] += f.x*w0.z + f.y*w1.z + f.z*w2.z + f.w*w3.z;
                    acc[n][3] += f.x*w0.w + f.y*w1.w + f.z*w2.w + f.w*w3.w;
                }
            }
        }
    }
    REDUCE1016(acc)
    {
        const float* bb = sign ? bb_neg : bb_pos;
        float4 b4 = *(const float4*)(bb + c0);
#pragma unroll
        for (int n=0;n<10;++n) {
            acc[n][0]+=b4.x; acc[n][1]+=b4.y; acc[n][2]+=b4.z; acc[n][3]+=b4.w;
            float s = acc[n][0]*acc[n][0]+acc[n][1]*acc[n][1]
                    + acc[n][2]*acc[n][2]+acc[n][3]*acc[n][3];
            s += __shfl_xor(s,1); s += __shfl_xor(s,2); s += __shfl_xor(s,4);
            float rn = 1.f / fmaxf(sqrtf(s), 1e-12f);
            if (g4 == 0) {
                Sh[sign][n][c0+0] = acc[n][0]*rn;
                Sh[sign][n][c0+1] = acc[n][1]*rn;
                Sh[sign][n][c0+2] = acc[n][2]*rn;
                Sh[sign][n][c0+3] = acc[n][3]*rn;
            }
        }
    }
    __syncthreads();

    // ---- two deep layers ----
    float* Sagg = Su;   // [6][10][32]
    for (int l = 0; l < 2; ++l) {
        // aggregates via adjacency matmul: thread owns (sign, cv)
        {
            float hs[10], ho[10];
#pragma unroll
            for (int m = 0; m < 10; ++m) {
                hs[m] = Sh[sign][m][cv];
                ho[m] = Sh[1-sign][m][cv];
            }
            const int aIn = 2*sign, aOut = 2*sign + 1;
#pragma unroll
            for (int n = 0; n < 10; ++n) {
                float ai = 0.f, ao = 0.f, ac = 0.f;
#pragma unroll
                for (int m = 0; m < 10; ++m) {
                    float w1 = Adj[aIn][n][m];
                    ai += w1 * hs[m];
                    ac += w1 * ho[m];
                    ao += Adj[aOut][n][m] * hs[m];
                }
                Sagg[(aIn*10 + n)*32 + cv]      = ai;
                Sagg[(aOut*10 + n)*32 + cv]     = ao;
                Sagg[((4+sign)*10 + n)*32 + cv] = ac;
            }
        }
        __syncthreads();

#pragma unroll
        for (int n=0;n<10;++n) { acc[n][0]=0.f; acc[n][1]=0.f; acc[n][2]=0.f; acc[n][3]=0.f; }
        {
            const float* ord[7];
            if (sign == 0) {
                ord[0]=Sagg+0*320; ord[1]=Sagg+1*320; ord[2]=Sagg+2*320;
                ord[3]=Sagg+3*320; ord[4]=Sagg+4*320;
                ord[5]=&Sh[0][0][0]; ord[6]=&Sh[1][0][0];
            } else {
                ord[0]=Sagg+2*320; ord[1]=Sagg+3*320; ord[2]=Sagg+0*320;
                ord[3]=Sagg+1*320; ord[4]=Sagg+5*320;
                ord[5]=&Sh[1][0][0]; ord[6]=&Sh[0][0][0];
            }
            const float* Wd = (sign ? Wd_neg : Wd_pos) + l*7168;
#pragma unroll
            for (int blk = 0; blk < 7; ++blk) {
                const float* bp = ord[blk] + kp;
                const float* wrow = Wd + (blk*32 + kp)*32 + c0;
#pragma unroll
                for (int kb = 0; kb < 2; ++kb) {
                    float4 w0 = *(const float4*)(wrow + (4*kb+0)*32);
                    float4 w1 = *(const float4*)(wrow + (4*kb+1)*32);
                    float4 w2 = *(const float4*)(wrow + (4*kb+2)*32);
                    float4 w3 = *(const float4*)(wrow + (4*kb+3)*32);
#pragma unroll
                    for (int n = 0; n < 10; ++n) {
                        float4 f = *(const float4*)(bp + n*32 + 4*kb);
                        acc[n][0] += f.x*w0.x + f.y*w1.x + f.z*w2.x + f.w*w3.x;
                        acc[n][1] += f.x*w0.y + f.y*w1.y + f.z*w2.y + f.w*w3.y;
                        acc[n][2] += f.x*w0.z + f.y*w1.z + f.z*w2.z + f.w*w3.z;
                        acc[n][3] += f.x*w0.w + f.y*w1.w + f.z*w2.w + f.w*w3.w;
                    }
                }
            }
        }
        REDUCE1016(acc)
        {
            const float* bd = (sign ? bd_neg : bd_pos) + l*32;
            float4 b4 = *(const float4*)(bd + c0);
#pragma unroll
            for (int n=0;n<10;++n) {
                float v0=acc[n][0]+b4.x, v1=acc[n][1]+b4.y,
                      v2=acc[n][2]+b4.z, v3=acc[n][3]+b4.w;
                float s = v0*v0+v1*v1+v2*v2+v3*v3;
                s += __shfl_xor(s,1); s += __shfl_xor(s,2); s += __shfl_xor(s,4);
                float rn = 1.f / fmaxf(sqrtf(s), 1e-12f);
                acc[n][0]=v0*rn; acc[n][1]=v1*rn; acc[n][2]=v2*rn; acc[n][3]=v3*rn;
            }
        }
        __syncthreads();    // all Sh/Sagg reads complete
        if (g4 == 0) {
#pragma unroll
            for (int n=0;n<10;++n) {
                Sh[sign][n][c0+0]=acc[n][0]; Sh[sign][n][c0+1]=acc[n][1];
                Sh[sign][n][c0+2]=acc[n][2]; Sh[sign][n][c0+3]=acc[n][3];
            }
        }
        __syncthreads();    // new Sh visible
    }

#pragma unroll
    for (int n = 0; n < 10; ++n) {
        float v = (tid < 32) ? Sh[0][n][tid] : Sh[1][n][tid-32];
        emb[(nb+n)*64 + tid] = v;
    }
}

// ---------------------------------------------------------------------------
// Persistent MFMA LSTM (unchanged from round 4/5).
// ---------------------------------------------------------------------------
__global__ __launch_bounds__(512) void lstm_mfma(
    const float* __restrict__ emb, const float* __restrict__ add_info,
    const short* __restrict__ wB, const float* __restrict__ wadd,
    const float* __restrict__ bsum, const float* __restrict__ hx0,
    const float* __restrict__ cx0, float* __restrict__ hbuf)
{
    __shared__ short aP[12288];          // [2][6][2][64][8] bf16 bits, 24.6 KB
    __shared__ float Sadd[2][32][2];
    const int tid = threadIdx.x;
    const int w  = tid >> 6;             // wave 0..7
    const int l  = tid & 63;
    const int li = l & 15;
    const int lk = l >> 4;
    const int R0 = blockIdx.x * 32;

    {
        int row = tid >> 4, j0 = (tid & 15) * 8;
        const float* hp = hx0 + (size_t)(R0 + row)*128 + j0;
        float4 h0 = *(const float4*)hp;
        float4 h1 = *(const float4*)(hp + 4);
        float v[8] = {h0.x,h0.y,h0.z,h0.w,h1.x,h1.y,h1.z,h1.w};
        short8v hi, lo;
#pragma unroll
        for (int e = 0; e < 8; ++e) {
            unsigned short hs = f2bf(v[e]);
            hi[e] = (short)hs;
            lo[e] = (short)f2bf(v[e] - bf2f(hs));
        }
        int mt = row >> 4, ln = (row & 15) + 16*((j0 >> 3) & 3), ki = j0 >> 5;
        *(short8v*)&aP[AIDX(0,ki,mt,ln)] = hi;
        *(short8v*)&aP[AIDX(1,ki,mt,ln)] = lo;
    }
    {
        int row = tid >> 4, d0 = (tid & 15)*4;
        int R = R0 + row, g = R/10, p = R - 10*g;
        float4 f = *(const float4*)&emb[((size_t)(g*TT + 0)*PP + p)*64 + d0];
        int k0 = 128 + d0;
        int mt = row>>4, ln = (row&15) + 16*((k0>>3)&3), ki = k0>>5, e0 = k0&7;
        float v[4] = {f.x,f.y,f.z,f.w};
        short4v hi, lo;
#pragma unroll
        for (int e = 0; e < 4; ++e) {
            unsigned short hs = f2bf(v[e]);
            hi[e] = (short)hs;
            lo[e] = (short)f2bf(v[e] - bf2f(hs));
        }
        *(short4v*)&aP[AIDX(0,ki,mt,ln)+e0] = hi;
        *(short4v*)&aP[AIDX(1,ki,mt,ln)+e0] = lo;
    }
    if (tid < 64) {
        int row = tid >> 1, cc = tid & 1;
        int R = R0 + row, g = R/10, p = R - 10*g;
        Sadd[0][row][cc] = add_info[((size_t)(g*MM + 0)*PP + p)*2 + cc];
    }
    float c[2][4];
#pragma unroll
    for (int mt = 0; mt < 2; ++mt)
#pragma unroll
        for (int r = 0; r < 4; ++r) {
            int row = mt*16 + lk*4 + r;
            c[mt][r] = cx0[(size_t)(R0+row)*128 + 16*w + li];
        }
    __syncthreads();

    for (int t = 0; t < TT; ++t) {
        f32x4 acc[2][4];
#pragma unroll
        for (int g = 0; g < 4; ++g) {
            float bs = bsum[t*512 + 128*g + 16*w + li];
            acc[0][g] = (f32x4){bs,bs,bs,bs};
            acc[1][g] = (f32x4){bs,bs,bs,bs};
        }
        const short* wt = wB + (size_t)t * WB_PER_T;
#pragma unroll 2
        for (int ki = 0; ki < 6; ++ki) {
            short8v ah0 = *(const short8v*)&aP[AIDX(0,ki,0,l)];
            short8v ah1 = *(const short8v*)&aP[AIDX(0,ki,1,l)];
            short8v al0 = *(const short8v*)&aP[AIDX(1,ki,0,l)];
            short8v al1 = *(const short8v*)&aP[AIDX(1,ki,1,l)];
#pragma unroll
            for (int g = 0; g < 4; ++g) {
                int nt = w + 8*g;
                short8v bh = *(const short8v*)(wt + (((size_t)ki*32 + nt)*64 + l)*8);
                short8v bl = *(const short8v*)(wt + (((size_t)(6+ki)*32 + nt)*64 + l)*8);
                acc[0][g] = __builtin_amdgcn_mfma_f32_16x16x32_bf16(ah0, bh, acc[0][g], 0, 0, 0);
                acc[0][g] = __builtin_amdgcn_mfma_f32_16x16x32_bf16(ah0, bl, acc[0][g], 0, 0, 0);
                acc[0][g] = __builtin_amdgcn_mfma_f32_16x16x32_bf16(al0, bh, acc[0][g], 0, 0, 0);
                acc[1][g] = __builtin_amdgcn_mfma_f32_16x16x32_bf16(ah1, bh, acc[1][g], 0, 0, 0);
                acc[1][g] = __builtin_amdgcn_mfma_f32_16x16x32_bf16(ah1, bl, acc[1][g], 0, 0, 0);
                acc[1][g] = __builtin_amdgcn_mfma_f32_16x16x32_bf16(al1, bh, acc[1][g], 0, 0, 0);
            }
        }
        __syncthreads();

        float wa0[4], wa1[4];
#pragma unroll
        for (int g = 0; g < 4; ++g) {
            wa0[g] = wadd[(size_t)(t*2+0)*512 + 128*g + 16*w + li];
            wa1[g] = wadd[(size_t)(t*2+1)*512 + 128*g + 16*w + li];
        }
        const int sb = t & 1;
        const int j  = 16*w + li;
        const int jsh = 16*((j >> 3) & 3);
        const int jki = j >> 5;
        const int je  = j & 7;
#pragma unroll
        for (int mt = 0; mt < 2; ++mt) {
#pragma unroll
            for (int r = 0; r < 4; ++r) {
                int row = mt*16 + lk*4 + r;
                float ad0 = Sadd[sb][row][0], ad1 = Sadd[sb][row][1];
                float v0 = acc[mt][0][r] + ad0*wa0[0] + ad1*wa1[0];
                float v1 = acc[mt][1][r] + ad0*wa0[1] + ad1*wa1[1];
                float v2 = acc[mt][2][r] + ad0*wa0[2] + ad1*wa1[2];
                float v3 = acc[mt][3][r] + ad0*wa0[3] + ad1*wa1[3];
                float iv = sigm(v0);
                float fv = sigm(v1);
                float gv = tanh_fast(v2);
                float ov = sigm(v3);
                float cn = fv*c[mt][r] + iv*gv;
                c[mt][r] = cn;
                float hv = ov*tanh_fast(cn);
                unsigned short hs = f2bf(hv);
                int ln = (row & 15) + jsh;
                aP[AIDX(0, jki, mt, ln) + je] = (short)hs;
                aP[AIDX(1, jki, mt, ln) + je] = (short)f2bf(hv - bf2f(hs));
                if (t == TT-1) hbuf[(size_t)(R0+row)*128 + j] = hv;
            }
        }
        if (t < TT-1) {
            int row = tid >> 4, d0 = (tid & 15)*4;
            int R = R0 + row, g = R/10, p = R - 10*g;
            float4 f = *(const float4*)&emb[((size_t)(g*TT + (t+1))*PP + p)*64 + d0];
            int k0 = 128 + d0;
            int mt = row>>4, ln = (row&15) + 16*((k0>>3)&3), ki = k0>>5, e0 = k0&7;
            float v[4] = {f.x,f.y,f.z,f.w};
            short4v hi, lo;
#pragma unroll
            for (int e = 0; e < 4; ++e) {
                unsigned short hs = f2bf(v[e]);
                hi[e] = (short)hs;
                lo[e] = (short)f2bf(v[e] - bf2f(hs));
            }
            *(short4v*)&aP[AIDX(0,ki,mt,ln)+e0] = hi;
            *(short4v*)&aP[AIDX(1,ki,mt,ln)+e0] = lo;
            if (tid < 64) {
                int rw = tid >> 1, cc = tid & 1;
                int R2 = R0 + rw, g2 = R2/10, p2 = R2 - 10*g2;
                Sadd[sb^1][rw][cc] =
                    add_info[((size_t)(g2*MM + (t+1)/MM)*PP + p2)*2 + cc];
            }
        }
        __syncthreads();
    }
}

// ---------------------------------------------------------------------------
// Final projection: out = h_last @ Wf + bf
// ---------------------------------------------------------------------------
__global__ __launch_bounds__(256) void final_proj(
    const float* __restrict__ hbuf, const float* __restrict__ Wf,
    const float* __restrict__ bf, float* __restrict__ out)
{
    __shared__ float wl[128*32];
    __shared__ float hl[64][128];
    const int tid = threadIdx.x;
    const int row0 = blockIdx.x * 64;
    for (int i = tid; i < 4096; i += 256) wl[i] = Wf[i];
    for (int i = tid; i < 8192; i += 256) hl[i>>7][i&127] = hbuf[row0*128 + i];
    __syncthreads();
    const int e  = tid & 31;
    const int rg = tid >> 5;
    float b = bf[e];
    float acc[8];
#pragma unroll
    for (int r=0;r<8;++r) acc[r] = b;
    for (int k = 0; k < 128; ++k) {
        float ww = wl[k*32 + e];
#pragma unroll
        for (int r=0;r<8;++r) acc[r] += hl[rg*8+r][k]*ww;
    }
#pragma unroll
    for (int r=0;r<8;++r) out[(row0 + rg*8 + r)*32 + e] = acc[r];
}

// ---------------------------------------------------------------------------
extern "C" void kernel_launch(void* const* d_in, const int* in_sizes, int n_in,
                              void* d_out, int out_size, void* d_ws, size_t ws_size,
                              hipStream_t stream)
{
    const float* x0       = (const float*)d_in[0];
    const float* add_info = (const float*)d_in[1];
    const float* Wb_pos   = (const float*)d_in[2];
    const float* bb_pos   = (const float*)d_in[3];
    const float* Wb_neg   = (const float*)d_in[4];
    const float* bb_neg   = (const float*)d_in[5];
    const float* Wd_pos   = (const float*)d_in[6];
    const float* bd_pos   = (const float*)d_in[7];
    const float* Wd_neg   = (const float*)d_in[8];
    const float* bd_neg   = (const float*)d_in[9];
    const float* W_ih     = (const float*)d_in[10];
    const float* W_hh     = (const float*)d_in[11];
    const float* b_ih     = (const float*)d_in[12];
    const float* b_hh     = (const float*)d_in[13];
    const float* hx0      = (const float*)d_in[14];
    const float* cx0      = (const float*)d_in[15];
    const float* Wf       = (const float*)d_in[16];
    const float* bf       = (const float*)d_in[17];
    const int*   pos_src  = (const int*)d_in[18];
    const int*   pos_dst  = (const int*)d_in[19];
    const int*   neg_src  = (const int*)d_in[20];
    const int*   neg_dst  = (const int*)d_in[21];

    float* ws    = (float*)d_ws;
    float* emb   = ws;                        // 8,192,000 f32
    float* hbuf  = emb   + 8192000;           //   655,360 f32
    float* bsumw = hbuf  + 655360;            //    12,800 f32
    float* waddw = bsumw + 12800;             //    25,600 f32
    short* wBw   = (short*)(waddw + 25600);   // 4,915,200 bf16-bits (~45.4 MiB total)

    hipLaunchKernelGGL(prep_kernel, dim3(2048), dim3(256), 0, stream,
                       W_ih, W_hh, b_ih, b_hh, wBw, waddw, bsumw);
    hipLaunchKernelGGL(graph_kernel, dim3(NGRAPH), dim3(64), 0, stream,
                       x0, Wb_pos, bb_pos, Wb_neg, bb_neg,
                       Wd_pos, bd_pos, Wd_neg, bd_neg,
                       pos_src, pos_dst, neg_src, neg_dst, emb);
    hipLaunchKernelGGL(lstm_mfma, dim3(160), dim3(512), 0, stream,
                       emb, add_info, wBw, waddw, bsumw, hx0, cx0, hbuf);
    hipLaunchKernelGGL(final_proj, dim3(80), dim3(256), 0, stream,
                       hbuf, Wf, bf, (float*)d_out);
}

// Round 9
// 493.859 us; speedup vs baseline: 2.2765x; 1.5856x over previous
//
#include <hip/hip_runtime.h>
#include <math.h>

#define GG 512
#define TT 25
#define PP 10
#define MM 5
#define EE 32
#define HID 32
#define HH 128
#define NEDGE 40
#define NGRAPH (GG*TT)          // 12800
#define NTOT (GG*TT*PP)         // 128000

typedef __attribute__((ext_vector_type(8))) short short8v;
typedef __attribute__((ext_vector_type(4))) short short4v;
typedef __attribute__((ext_vector_type(4))) float f32x4;

// lstm A-panel LDS index: [s][ki<6][mt<2][lane<64][e<8] (shorts)
#define AIDX(s,ki,mt,l) (((((s)*6+(ki))*2+(mt))*64+(l))*8)
#define WB_PER_T 196608   // 2*6*32*64*8

// graph A-panel indices within U[10240] shorts (layouts used at disjoint times)
#define AXI(sp,mt,ki) ((((sp)*5+(mt))*2+(ki))*512)
#define AHI(sp,wh,mt) ((((sp)*2+(wh))*5+(mt))*512)
#define NWG 73728         // 36 units * 2(sp) * 2(nt) * 64 * 8

#define MFMA16(a,b,c) __builtin_amdgcn_mfma_f32_16x16x32_bf16(a,b,c,0,0,0)

__device__ __forceinline__ unsigned short f2bf(float x){
    unsigned u = __float_as_uint(x);
    u += 0x7fffu + ((u >> 16) & 1u);
    return (unsigned short)(u >> 16);
}
__device__ __forceinline__ float bf2f(unsigned short s){
    return __uint_as_float(((unsigned)s) << 16);
}
__device__ __forceinline__ float sigm(float x){ return 1.f/(1.f+__expf(-x)); }
__device__ __forceinline__ float tanh_fast(float x){
    float ax = fabsf(x);
    float e  = __expf(-2.f*ax);
    float t  = (1.f-e)/(1.f+e);
    return copysignf(t, x);
}

// ---------------------------------------------------------------------------
// Prep: LSTM weight frags (as before) + graph-GEMM B-fragments wG.
// wG unit u: [sp(hi/lo)][nt(2)][lane(64)][e(8)], k = (l>>4)*8+e, n = nt*16+(l&15)
//   u<8: base: sgn=u>>2, prod=(u>>1)&1 (0=mean rows 0-63, 1=self rows 64-127), ki=u&1
//   u>=8: deep: v=u-8: wid=v%7, sgn=(v/7)&1, lyr=v/14 -> Wd_sgn[lyr] block wid
// ---------------------------------------------------------------------------
__global__ void prep_kernel(const float* __restrict__ W_ih, const float* __restrict__ W_hh,
                            const float* __restrict__ b_ih, const float* __restrict__ b_hh,
                            const float* __restrict__ Wb_pos, const float* __restrict__ Wb_neg,
                            const float* __restrict__ Wd_pos, const float* __restrict__ Wd_neg,
                            short* __restrict__ wB, float* __restrict__ wadd,
                            float* __restrict__ bsum, short* __restrict__ wG)
{
    const int NW = TT*WB_PER_T;          // 4,915,200
    const int NA = TT*2*512;             // 25,600
    const int NB = TT*512;               // 12,800
    const int total = NW + NA + NB + NWG;
    for (int idx = blockIdx.x*blockDim.x + threadIdx.x; idx < total;
         idx += gridDim.x*blockDim.x) {
        if (idx < NW) {
            int e  = idx & 7;
            int l  = (idx >> 3) & 63;
            int nt = (idx >> 9) & 31;
            int rest = idx >> 14;        // (t*2+s)*6 + ki
            int ki = rest % 6; rest /= 6;
            int s  = rest & 1;
            int t  = rest >> 1;
            int k  = ki*32 + (l >> 4)*8 + e;
            int n  = nt*16 + (l & 15);
            float wv = (k < 128) ? W_hh[(size_t)(t*512 + n)*128 + k]
                                 : W_ih[(size_t)(t*512 + n)*66 + (k - 128)];
            unsigned short hi = f2bf(wv);
            unsigned short outv = (s == 0) ? hi : f2bf(wv - bf2f(hi));
            wB[idx] = (short)outv;
        } else if (idx < NW + NA) {
            int i2 = idx - NW;
            int t = i2 / 1024, r = i2 % 1024;
            int cc = r >> 9, n = r & 511;
            wadd[i2] = W_ih[(size_t)(t*512 + n)*66 + 64 + cc];
        } else if (idx < NW + NA + NB) {
            int i3 = idx - NW - NA;
            bsum[i3] = b_ih[i3] + b_hh[i3];
        } else {
            int i4 = idx - NW - NA - NB;     // < 73728
            int e  = i4 & 7;
            int ll = (i4 >> 3) & 63;
            int nt = (i4 >> 9) & 1;
            int sp = (i4 >> 10) & 1;
            int u  = i4 >> 11;               // 0..35
            int n  = nt*16 + (ll & 15);
            int krow = (ll >> 4)*8 + e;
            float wv;
            if (u < 8) {
                int sgn = u >> 2, prod = (u >> 1) & 1, ki = u & 1;
                const float* Wb = sgn ? Wb_neg : Wb_pos;
                wv = Wb[(prod*64 + ki*32 + krow)*32 + n];
            } else {
                int v = u - 8;
                int wid = v % 7, sgn = (v / 7) & 1, lyr = v / 14;
                const float* Wd = (sgn ? Wd_neg : Wd_pos) + lyr*7168;
                wv = Wd[(wid*32 + krow)*32 + n];
            }
            unsigned short hi = f2bf(wv);
            wG[i4] = (sp == 0) ? (short)hi : (short)f2bf(wv - bf2f(hi));
        }
    }
}

// ---------------------------------------------------------------------------
// Graph kernel v6: batched MFMA. 8 graphs per 256-thread block (4 waves).
// All seg_means via Adj@(H@W): GEMMs on matrix cores (split-bf16, 3 MFMA),
// per-bucket Y[2][80][36] staged in LDS, VALU Adj-apply into 20 regs/thread.
// ---------------------------------------------------------------------------
__global__ __launch_bounds__(256) void graph_kernel(
    const float* __restrict__ x0,
    const float* __restrict__ bb_pos, const float* __restrict__ bb_neg,
    const float* __restrict__ bd_pos, const float* __restrict__ bd_neg,
    const short* __restrict__ wG,
    const int* __restrict__ pos_src, const int* __restrict__ pos_dst,
    const int* __restrict__ neg_src, const int* __restrict__ neg_dst,
    float* __restrict__ emb)
{
    __shared__ short U[10240];           // 20480 B: ax frags, then aH frags
    __shared__ float Yf[5760];           // 23040 B: [2][80][36]; early: Ses/Cm/Scnt
    __shared__ float Adj[8][4][10][10];  // 12800 B

    const int tid = threadIdx.x;
    const int w   = tid >> 6;
    const int l   = tid & 63;
    const int li  = l & 15;
    const int lk  = l >> 4;
    const int s   = tid >> 7;            // output sign this thread owns
    const int rg  = (tid >> 3) & 15;     // row group (5 rows)
    const int c4  = tid & 7;             // 4-col group
    const int gq  = rg >> 1;             // graph (block-local)
    const int nbase = (rg & 1)*5;        // node base within graph

    // ---- stage x0 -> AX fragments (hi/lo bf16) ----
    for (int i = tid; i < 1280; i += 256) {      // 80 rows x 16 float4
        int row = i >> 4, kq = i & 15;
        float4 f = ((const float4*)x0)[(size_t)blockIdx.x*1280 + i];
        int k0 = kq*4;
        int ln = (row & 15) + 16*((k0 >> 3) & 3);
        int ki = k0 >> 5, e0 = k0 & 7, mt = row >> 4;
        float vv[4] = {f.x, f.y, f.z, f.w};
        short4v hi4, lo4;
#pragma unroll
        for (int e2 = 0; e2 < 4; ++e2) {
            unsigned short h2 = f2bf(vv[e2]);
            hi4[e2] = (short)h2;
            lo4[e2] = (short)f2bf(vv[e2] - bf2f(h2));
        }
        *(short4v*)&U[AXI(0,mt,ki) + ln*8 + e0] = hi4;
        *(short4v*)&U[AXI(1,mt,ki) + ln*8 + e0] = lo4;
    }

    // ---- edges / counts / adjacency (in Yf region, dead later) ----
    int*   Ses  = (int*)Yf;              // [8][4][40] = 1280
    float* Cm   = Yf + 1280;             // [8][2][100] = 1600
    float* Scnt = Yf + 2880;             // [8][4][10]  = 320
    for (int i = tid; i < 1280; i += 256) {
        int g = i / 160, r = i % 160, b = r / 40, e = r % 40;
        const int* p = (b==0)?pos_src:(b==1)?pos_dst:(b==2)?neg_src:neg_dst;
        Ses[i] = p[(blockIdx.x*8 + g)*40 + e];
    }
    for (int i = tid; i < 1600; i += 256) Cm[i] = 0.f;
    __syncthreads();
    for (int i = tid; i < 640; i += 256) {
        int g = i / 80, r = i % 80, si = r / 40, e = r % 40;
        int src = Ses[g*160 + (2*si)*40 + e];
        int dst = Ses[g*160 + (2*si+1)*40 + e];
        atomicAdd(&Cm[(g*2 + si)*100 + src*10 + dst], 1.f);
    }
    __syncthreads();
    for (int i = tid; i < 320; i += 256) {
        int g = i / 40, r = i % 40, b = r / 10, n = r % 10;
        int si = b >> 1, isCol = b & 1;
        float ssum = 0.f;
        for (int m = 0; m < 10; ++m)
            ssum += isCol ? Cm[(g*2+si)*100 + m*10 + n] : Cm[(g*2+si)*100 + n*10 + m];
        Scnt[i] = fmaxf(ssum, 1.f);
    }
    __syncthreads();
    for (int i = tid; i < 3200; i += 256) {
        int g = i / 400, r = i % 400, a = r / 100, rr = r % 100;
        int n = rr / 10, m = rr % 10;
        int si = a >> 1, isOut = a & 1;
        float cv = isOut ? Cm[(g*2+si)*100 + m*10 + n] : Cm[(g*2+si)*100 + n*10 + m];
        Adj[g][a][n][m] = cv / Scnt[g*40 + a*10 + n];
    }
    __syncthreads();   // Adj ready; Yf free

    f32x4 acc2[5];

    // =================== base layer ===================
    {
        const float* bb = s ? bb_neg : bb_pos;
        f32x4 b4 = *(const f32x4*)(bb + c4*4);
#pragma unroll
        for (int jj = 0; jj < 5; ++jj) acc2[jj] = b4;
    }
    for (int prod = 0; prod < 2; ++prod) {      // 0 = mean bucket, 1 = self
        for (int i = 0; i < 5; ++i) {
            int jid = w*5 + i;
            int sgn = (jid >= 10);
            int rem = jid - 10*sgn;
            int nt  = (rem >= 5);
            int mt2 = rem - 5*nt;
            f32x4 cf = {0.f, 0.f, 0.f, 0.f};
            for (int ki = 0; ki < 2; ++ki) {
                short8v ah = *(const short8v*)&U[AXI(0,mt2,ki) + l*8];
                short8v al = *(const short8v*)&U[AXI(1,mt2,ki) + l*8];
                int u = sgn*4 + prod*2 + ki;
                const short* wp = wG + ((((size_t)u*2 + 0)*2 + nt)*64 + l)*8;
                short8v bh = *(const short8v*)wp;
                short8v bl = *(const short8v*)(wp + 1024);
                cf = MFMA16(ah, bh, cf);
                cf = MFMA16(ah, bl, cf);
                cf = MFMA16(al, bh, cf);
            }
#pragma unroll
            for (int r = 0; r < 4; ++r)
                Yf[(sgn*80 + mt2*16 + lk*4 + r)*36 + nt*16 + li] = cf[r];
        }
        __syncthreads();
        if (prod == 0) {
            int a = 2*s;
            for (int m = 0; m < 10; ++m) {
                f32x4 y = *(const f32x4*)&Yf[(s*80 + gq*10 + m)*36 + c4*4];
#pragma unroll
                for (int jj = 0; jj < 5; ++jj)
                    acc2[jj] += Adj[gq][a][nbase+jj][m] * y;
            }
        } else {
#pragma unroll
            for (int jj = 0; jj < 5; ++jj)
                acc2[jj] += *(const f32x4*)&Yf[(s*80 + rg*5 + jj)*36 + c4*4];
        }
        __syncthreads();
    }
    // base epilogue: l2norm + write aH frags (hi/lo)
#pragma unroll
    for (int jj = 0; jj < 5; ++jj) {
        f32x4 v = acc2[jj];
        float ss = v[0]*v[0] + v[1]*v[1] + v[2]*v[2] + v[3]*v[3];
        ss += __shfl_xor(ss,1); ss += __shfl_xor(ss,2); ss += __shfl_xor(ss,4);
        float rn = 1.f / fmaxf(sqrtf(ss), 1e-12f);
        v *= rn;
        int row = rg*5 + jj;
        int mt2 = row >> 4;
        int k0 = c4*4;
        int ln = (row & 15) + 16*((k0 >> 3) & 3);
        float vv[4] = {v[0], v[1], v[2], v[3]};
        short4v hi4, lo4;
#pragma unroll
        for (int e2 = 0; e2 < 4; ++e2) {
            unsigned short h2 = f2bf(vv[e2]);
            hi4[e2] = (short)h2;
            lo4[e2] = (short)f2bf(vv[e2] - bf2f(h2));
        }
        *(short4v*)&U[AHI(0,s,mt2) + ln*8 + (k0 & 7)] = hi4;
        *(short4v*)&U[AHI(1,s,mt2) + ln*8 + (k0 & 7)] = lo4;
    }
    __syncthreads();

    // =================== two deep layers ===================
    for (int lyr = 0; lyr < 2; ++lyr) {
        {
            const float* bd = (s ? bd_neg : bd_pos) + lyr*32;
            f32x4 b4 = *(const f32x4*)(bd + c4*4);
#pragma unroll
            for (int jj = 0; jj < 5; ++jj) acc2[jj] = b4;
        }
        for (int b = 0; b < 5; ++b) {
            // bucket b: 0:{W0(hs),W4(ho)} a=2s | 1:{W1(hs)} a=2s+1 |
            //           2:{W2(ho)} a=2-2s | 3:{W3(ho)} a=3-2s | 4:self {W5(hs),W6(ho)}
            const int np   = (b == 0 || b == 4) ? 2 : 1;
            const int rel0 = (b == 2 || b == 3) ? 1 : 0;
            const int wid0 = (b == 4) ? 5 : b;
            for (int i = 0; i < 5; ++i) {
                int jid = w*5 + i;
                int sgn = (jid >= 10);
                int rem = jid - 10*sgn;
                int nt  = (rem >= 5);
                int mt2 = rem - 5*nt;
                f32x4 cf = {0.f, 0.f, 0.f, 0.f};
                {
                    int wh = sgn ^ rel0;
                    int u = 8 + (lyr*2 + sgn)*7 + wid0;
                    short8v ah = *(const short8v*)&U[AHI(0,wh,mt2) + l*8];
                    short8v al = *(const short8v*)&U[AHI(1,wh,mt2) + l*8];
                    const short* wp = wG + ((((size_t)u*2 + 0)*2 + nt)*64 + l)*8;
                    short8v bh = *(const short8v*)wp;
                    short8v bl = *(const short8v*)(wp + 1024);
                    cf = MFMA16(ah, bh, cf);
                    cf = MFMA16(ah, bl, cf);
                    cf = MFMA16(al, bh, cf);
                }
                if (np == 2) {
                    int wid1 = (b == 0) ? 4 : 6;
                    int wh = sgn ^ 1;
                    int u = 8 + (lyr*2 + sgn)*7 + wid1;
                    short8v ah = *(const short8v*)&U[AHI(0,wh,mt2) + l*8];
                    short8v al = *(const short8v*)&U[AHI(1,wh,mt2) + l*8];
                    const short* wp = wG + ((((size_t)u*2 + 0)*2 + nt)*64 + l)*8;
                    short8v bh = *(const short8v*)wp;
                    short8v bl = *(const short8v*)(wp + 1024);
                    cf = MFMA16(ah, bh, cf);
                    cf = MFMA16(ah, bl, cf);
                    cf = MFMA16(al, bh, cf);
                }
#pragma unroll
                for (int r = 0; r < 4; ++r)
                    Yf[(sgn*80 + mt2*16 + lk*4 + r)*36 + nt*16 + li] = cf[r];
            }
            __syncthreads();
            if (b < 4) {
                int a = (b == 0) ? 2*s : (b == 1) ? 2*s + 1 : (b == 2) ? 2 - 2*s : 3 - 2*s;
                for (int m = 0; m < 10; ++m) {
                    f32x4 y = *(const f32x4*)&Yf[(s*80 + gq*10 + m)*36 + c4*4];
#pragma unroll
                    for (int jj = 0; jj < 5; ++jj)
                        acc2[jj] += Adj[gq][a][nbase+jj][m] * y;
                }
            } else {
#pragma unroll
                for (int jj = 0; jj < 5; ++jj)
                    acc2[jj] += *(const f32x4*)&Yf[(s*80 + rg*5 + jj)*36 + c4*4];
            }
            __syncthreads();
        }
        // epilogue: l2norm; write aH (lyr 0) or emb (lyr 1)
#pragma unroll
        for (int jj = 0; jj < 5; ++jj) {
            f32x4 v = acc2[jj];
            float ss = v[0]*v[0] + v[1]*v[1] + v[2]*v[2] + v[3]*v[3];
            ss += __shfl_xor(ss,1); ss += __shfl_xor(ss,2); ss += __shfl_xor(ss,4);
            float rn = 1.f / fmaxf(sqrtf(ss), 1e-12f);
            v *= rn;
            int row = rg*5 + jj;
            if (lyr == 0) {
                int mt2 = row >> 4;
                int k0 = c4*4;
                int ln = (row & 15) + 16*((k0 >> 3) & 3);
                float vv[4] = {v[0], v[1], v[2], v[3]};
                short4v hi4, lo4;
#pragma unroll
                for (int e2 = 0; e2 < 4; ++e2) {
                    unsigned short h2 = f2bf(vv[e2]);
                    hi4[e2] = (short)h2;
                    lo4[e2] = (short)f2bf(vv[e2] - bf2f(h2));
                }
                *(short4v*)&U[AHI(0,s,mt2) + ln*8 + (k0 & 7)] = hi4;
                *(short4v*)&U[AHI(1,s,mt2) + ln*8 + (k0 & 7)] = lo4;
            } else {
                *(f32x4*)&emb[((size_t)(blockIdx.x*80 + row))*64 + s*32 + c4*4] = v;
            }
        }
        __syncthreads();
    }
}

// ---------------------------------------------------------------------------
// Persistent MFMA LSTM (unchanged — known good).
// ---------------------------------------------------------------------------
__global__ __launch_bounds__(512) void lstm_mfma(
    const float* __restrict__ emb, const float* __restrict__ add_info,
    const short* __restrict__ wB, const float* __restrict__ wadd,
    const float* __restrict__ bsum, const float* __restrict__ hx0,
    const float* __restrict__ cx0, float* __restrict__ hbuf)
{
    __shared__ short aP[12288];          // [2][6][2][64][8] bf16 bits, 24.6 KB
    __shared__ float Sadd[2][32][2];
    const int tid = threadIdx.x;
    const int w  = tid >> 6;             // wave 0..7
    const int l  = tid & 63;
    const int li = l & 15;
    const int lk = l >> 4;
    const int R0 = blockIdx.x * 32;

    {
        int row = tid >> 4, j0 = (tid & 15) * 8;
        const float* hp = hx0 + (size_t)(R0 + row)*128 + j0;
        float4 h0 = *(const float4*)hp;
        float4 h1 = *(const float4*)(hp + 4);
        float v[8] = {h0.x,h0.y,h0.z,h0.w,h1.x,h1.y,h1.z,h1.w};
        short8v hi, lo;
#pragma unroll
        for (int e = 0; e < 8; ++e) {
            unsigned short hs = f2bf(v[e]);
            hi[e] = (short)hs;
            lo[e] = (short)f2bf(v[e] - bf2f(hs));
        }
        int mt = row >> 4, ln = (row & 15) + 16*((j0 >> 3) & 3), ki = j0 >> 5;
        *(short8v*)&aP[AIDX(0,ki,mt,ln)] = hi;
        *(short8v*)&aP[AIDX(1,ki,mt,ln)] = lo;
    }
    {
        int row = tid >> 4, d0 = (tid & 15)*4;
        int R = R0 + row, g = R/10, p = R - 10*g;
        float4 f = *(const float4*)&emb[((size_t)(g*TT + 0)*PP + p)*64 + d0];
        int k0 = 128 + d0;
        int mt = row>>4, ln = (row&15) + 16*((k0>>3)&3), ki = k0>>5, e0 = k0&7;
        float v[4] = {f.x,f.y,f.z,f.w};
        short4v hi, lo;
#pragma unroll
        for (int e = 0; e < 4; ++e) {
            unsigned short hs = f2bf(v[e]);
            hi[e] = (short)hs;
            lo[e] = (short)f2bf(v[e] - bf2f(hs));
        }
        *(short4v*)&aP[AIDX(0,ki,mt,ln)+e0] = hi;
        *(short4v*)&aP[AIDX(1,ki,mt,ln)+e0] = lo;
    }
    if (tid < 64) {
        int row = tid >> 1, cc = tid & 1;
        int R = R0 + row, g = R/10, p = R - 10*g;
        Sadd[0][row][cc] = add_info[((size_t)(g*MM + 0)*PP + p)*2 + cc];
    }
    float c[2][4];
#pragma unroll
    for (int mt = 0; mt < 2; ++mt)
#pragma unroll
        for (int r = 0; r < 4; ++r) {
            int row = mt*16 + lk*4 + r;
            c[mt][r] = cx0[(size_t)(R0+row)*128 + 16*w + li];
        }
    __syncthreads();

    for (int t = 0; t < TT; ++t) {
        f32x4 acc[2][4];
#pragma unroll
        for (int g = 0; g < 4; ++g) {
            float bs = bsum[t*512 + 128*g + 16*w + li];
            acc[0][g] = (f32x4){bs,bs,bs,bs};
            acc[1][g] = (f32x4){bs,bs,bs,bs};
        }
        const short* wt = wB + (size_t)t * WB_PER_T;
#pragma unroll 2
        for (int ki = 0; ki < 6; ++ki) {
            short8v ah0 = *(const short8v*)&aP[AIDX(0,ki,0,l)];
            short8v ah1 = *(const short8v*)&aP[AIDX(0,ki,1,l)];
            short8v al0 = *(const short8v*)&aP[AIDX(1,ki,0,l)];
            short8v al1 = *(const short8v*)&aP[AIDX(1,ki,1,l)];
#pragma unroll
            for (int g = 0; g < 4; ++g) {
                int nt = w + 8*g;
                short8v bh = *(const short8v*)(wt + (((size_t)ki*32 + nt)*64 + l)*8);
                short8v bl = *(const short8v*)(wt + (((size_t)(6+ki)*32 + nt)*64 + l)*8);
                acc[0][g] = MFMA16(ah0, bh, acc[0][g]);
                acc[0][g] = MFMA16(ah0, bl, acc[0][g]);
                acc[0][g] = MFMA16(al0, bh, acc[0][g]);
                acc[1][g] = MFMA16(ah1, bh, acc[1][g]);
                acc[1][g] = MFMA16(ah1, bl, acc[1][g]);
                acc[1][g] = MFMA16(al1, bh, acc[1][g]);
            }
        }
        __syncthreads();

        float wa0[4], wa1[4];
#pragma unroll
        for (int g = 0; g < 4; ++g) {
            wa0[g] = wadd[(size_t)(t*2+0)*512 + 128*g + 16*w + li];
            wa1[g] = wadd[(size_t)(t*2+1)*512 + 128*g + 16*w + li];
        }
        const int sb = t & 1;
        const int j  = 16*w + li;
        const int jsh = 16*((j >> 3) & 3);
        const int jki = j >> 5;
        const int je  = j & 7;
#pragma unroll
        for (int mt = 0; mt < 2; ++mt) {
#pragma unroll
            for (int r = 0; r < 4; ++r) {
                int row = mt*16 + lk*4 + r;
                float ad0 = Sadd[sb][row][0], ad1 = Sadd[sb][row][1];
                float v0 = acc[mt][0][r] + ad0*wa0[0] + ad1*wa1[0];
                float v1 = acc[mt][1][r] + ad0*wa0[1] + ad1*wa1[1];
                float v2 = acc[mt][2][r] + ad0*wa0[2] + ad1*wa1[2];
                float v3 = acc[mt][3][r] + ad0*wa0[3] + ad1*wa1[3];
                float iv = sigm(v0);
                float fv = sigm(v1);
                float gv = tanh_fast(v2);
                float ov = sigm(v3);
                float cn = fv*c[mt][r] + iv*gv;
                c[mt][r] = cn;
                float hv = ov*tanh_fast(cn);
                unsigned short hs = f2bf(hv);
                int ln = (row & 15) + jsh;
                aP[AIDX(0, jki, mt, ln) + je] = (short)hs;
                aP[AIDX(1, jki, mt, ln) + je] = (short)f2bf(hv - bf2f(hs));
                if (t == TT-1) hbuf[(size_t)(R0+row)*128 + j] = hv;
            }
        }
        if (t < TT-1) {
            int row = tid >> 4, d0 = (tid & 15)*4;
            int R = R0 + row, g = R/10, p = R - 10*g;
            float4 f = *(const float4*)&emb[((size_t)(g*TT + (t+1))*PP + p)*64 + d0];
            int k0 = 128 + d0;
            int mt = row>>4, ln = (row&15) + 16*((k0>>3)&3), ki = k0>>5, e0 = k0&7;
            float v[4] = {f.x,f.y,f.z,f.w};
            short4v hi, lo;
#pragma unroll
            for (int e = 0; e < 4; ++e) {
                unsigned short hs = f2bf(v[e]);
                hi[e] = (short)hs;
                lo[e] = (short)f2bf(v[e] - bf2f(hs));
            }
            *(short4v*)&aP[AIDX(0,ki,mt,ln)+e0] = hi;
            *(short4v*)&aP[AIDX(1,ki,mt,ln)+e0] = lo;
            if (tid < 64) {
                int rw = tid >> 1, cc = tid & 1;
                int R2 = R0 + rw, g2 = R2/10, p2 = R2 - 10*g2;
                Sadd[sb^1][rw][cc] =
                    add_info[((size_t)(g2*MM + (t+1)/MM)*PP + p2)*2 + cc];
            }
        }
        __syncthreads();
    }
}

// ---------------------------------------------------------------------------
// Final projection: out = h_last @ Wf + bf
// ---------------------------------------------------------------------------
__global__ __launch_bounds__(256) void final_proj(
    const float* __restrict__ hbuf, const float* __restrict__ Wf,
    const float* __restrict__ bf, float* __restrict__ out)
{
    __shared__ float wl[128*32];
    __shared__ float hl[64][128];
    const int tid = threadIdx.x;
    const int row0 = blockIdx.x * 64;
    for (int i = tid; i < 4096; i += 256) wl[i] = Wf[i];
    for (int i = tid; i < 8192; i += 256) hl[i>>7][i&127] = hbuf[row0*128 + i];
    __syncthreads();
    const int e  = tid & 31;
    const int rg = tid >> 5;
    float b = bf[e];
    float acc[8];
#pragma unroll
    for (int r=0;r<8;++r) acc[r] = b;
    for (int k = 0; k < 128; ++k) {
        float ww = wl[k*32 + e];
#pragma unroll
        for (int r=0;r<8;++r) acc[r] += hl[rg*8+r][k]*ww;
    }
#pragma unroll
    for (int r=0;r<8;++r) out[(row0 + rg*8 + r)*32 + e] = acc[r];
}

// ---------------------------------------------------------------------------
extern "C" void kernel_launch(void* const* d_in, const int* in_sizes, int n_in,
                              void* d_out, int out_size, void* d_ws, size_t ws_size,
                              hipStream_t stream)
{
    const float* x0       = (const float*)d_in[0];
    const float* add_info = (const float*)d_in[1];
    const float* Wb_pos   = (const float*)d_in[2];
    const float* bb_pos   = (const float*)d_in[3];
    const float* Wb_neg   = (const float*)d_in[4];
    const float* bb_neg   = (const float*)d_in[5];
    const float* Wd_pos   = (const float*)d_in[6];
    const float* bd_pos   = (const float*)d_in[7];
    const float* Wd_neg   = (const float*)d_in[8];
    const float* bd_neg   = (const float*)d_in[9];
    const float* W_ih     = (const float*)d_in[10];
    const float* W_hh     = (const float*)d_in[11];
    const float* b_ih     = (const float*)d_in[12];
    const float* b_hh     = (const float*)d_in[13];
    const float* hx0      = (const float*)d_in[14];
    const float* cx0      = (const float*)d_in[15];
    const float* Wf       = (const float*)d_in[16];
    const float* bf       = (const float*)d_in[17];
    const int*   pos_src  = (const int*)d_in[18];
    const int*   pos_dst  = (const int*)d_in[19];
    const int*   neg_src  = (const int*)d_in[20];
    const int*   neg_dst  = (const int*)d_in[21];

    float* ws    = (float*)d_ws;
    float* emb   = ws;                        // 8,192,000 f32
    float* hbuf  = emb   + 8192000;           //   655,360 f32
    float* bsumw = hbuf  + 655360;            //    12,800 f32
    float* waddw = bsumw + 12800;             //    25,600 f32
    short* wBw   = (short*)(waddw + 25600);   // 4,915,200 shorts
    short* wGw   = wBw + 4915200;             //    73,728 shorts (~45.6 MiB total)

    hipLaunchKernelGGL(prep_kernel, dim3(2048), dim3(256), 0, stream,
                       W_ih, W_hh, b_ih, b_hh, Wb_pos, Wb_neg, Wd_pos, Wd_neg,
                       wBw, waddw, bsumw, wGw);
    hipLaunchKernelGGL(graph_kernel, dim3(NGRAPH/8), dim3(256), 0, stream,
                       x0, bb_pos, bb_neg, bd_pos, bd_neg, wGw,
                       pos_src, pos_dst, neg_src, neg_dst, emb);
    hipLaunchKernelGGL(lstm_mfma, dim3(160), dim3(512), 0, stream,
                       emb, add_info, wBw, waddw, bsumw, hx0, cx0, hbuf);
    hipLaunchKernelGGL(final_proj, dim3(80), dim3(256), 0, stream,
                       hbuf, Wf, bf, (float*)d_out);
}

// Round 10
// 397.738 us; speedup vs baseline: 2.8266x; 1.2417x over previous
//
#include <hip/hip_runtime.h>
#include <math.h>

#define GG 512
#define TT 25
#define PP 10
#define MM 5
#define EE 32
#define HID 32
#define HH 128
#define NEDGE 40
#define NGRAPH (GG*TT)          // 12800
#define NTOT (GG*TT*PP)         // 128000

typedef __attribute__((ext_vector_type(8))) short short8v;
typedef __attribute__((ext_vector_type(4))) short short4v;
typedef __attribute__((ext_vector_type(4))) float f32x4;

// lstm A-panel LDS index: [s][ki<6][mt<2][lane<64][e<8] (shorts)
#define AIDX(s,ki,mt,l) (((((s)*6+(ki))*2+(mt))*64+(l))*8)
#define WB_PER_T 196608   // 2*6*32*64*8

// graph A-panel indices within U[10240] shorts (layouts used at disjoint times)
#define AXI(sp,mt,ki) ((((sp)*5+(mt))*2+(ki))*512)
#define AHI(sp,wh,mt) ((((sp)*2+(wh))*5+(mt))*512)
#define NWG 73728         // 36 units * 2(sp) * 2(nt) * 64 * 8

#define MFMA16(a,b,c) __builtin_amdgcn_mfma_f32_16x16x32_bf16(a,b,c,0,0,0)

__device__ __forceinline__ unsigned short f2bf(float x){
    unsigned u = __float_as_uint(x);
    u += 0x7fffu + ((u >> 16) & 1u);
    return (unsigned short)(u >> 16);
}
__device__ __forceinline__ float bf2f(unsigned short s){
    return __uint_as_float(((unsigned)s) << 16);
}
__device__ __forceinline__ float sigm(float x){ return 1.f/(1.f+__expf(-x)); }
__device__ __forceinline__ float tanh_fast(float x){
    float ax = fabsf(x);
    float e  = __expf(-2.f*ax);
    float t  = (1.f-e)/(1.f+e);
    return copysignf(t, x);
}

// ---------------------------------------------------------------------------
// Prep: LSTM weight frags + graph-GEMM B-fragments wG. (unchanged from r9)
// ---------------------------------------------------------------------------
__global__ void prep_kernel(const float* __restrict__ W_ih, const float* __restrict__ W_hh,
                            const float* __restrict__ b_ih, const float* __restrict__ b_hh,
                            const float* __restrict__ Wb_pos, const float* __restrict__ Wb_neg,
                            const float* __restrict__ Wd_pos, const float* __restrict__ Wd_neg,
                            short* __restrict__ wB, float* __restrict__ wadd,
                            float* __restrict__ bsum, short* __restrict__ wG)
{
    const int NW = TT*WB_PER_T;          // 4,915,200
    const int NA = TT*2*512;             // 25,600
    const int NB = TT*512;               // 12,800
    const int total = NW + NA + NB + NWG;
    for (int idx = blockIdx.x*blockDim.x + threadIdx.x; idx < total;
         idx += gridDim.x*blockDim.x) {
        if (idx < NW) {
            int e  = idx & 7;
            int l  = (idx >> 3) & 63;
            int nt = (idx >> 9) & 31;
            int rest = idx >> 14;        // (t*2+s)*6 + ki
            int ki = rest % 6; rest /= 6;
            int s  = rest & 1;
            int t  = rest >> 1;
            int k  = ki*32 + (l >> 4)*8 + e;
            int n  = nt*16 + (l & 15);
            float wv = (k < 128) ? W_hh[(size_t)(t*512 + n)*128 + k]
                                 : W_ih[(size_t)(t*512 + n)*66 + (k - 128)];
            unsigned short hi = f2bf(wv);
            unsigned short outv = (s == 0) ? hi : f2bf(wv - bf2f(hi));
            wB[idx] = (short)outv;
        } else if (idx < NW + NA) {
            int i2 = idx - NW;
            int t = i2 / 1024, r = i2 % 1024;
            int cc = r >> 9, n = r & 511;
            wadd[i2] = W_ih[(size_t)(t*512 + n)*66 + 64 + cc];
        } else if (idx < NW + NA + NB) {
            int i3 = idx - NW - NA;
            bsum[i3] = b_ih[i3] + b_hh[i3];
        } else {
            int i4 = idx - NW - NA - NB;     // < 73728
            int e  = i4 & 7;
            int ll = (i4 >> 3) & 63;
            int nt = (i4 >> 9) & 1;
            int sp = (i4 >> 10) & 1;
            int u  = i4 >> 11;               // 0..35
            int n  = nt*16 + (ll & 15);
            int krow = (ll >> 4)*8 + e;
            float wv;
            if (u < 8) {
                int sgn = u >> 2, prod = (u >> 1) & 1, ki = u & 1;
                const float* Wb = sgn ? Wb_neg : Wb_pos;
                wv = Wb[(prod*64 + ki*32 + krow)*32 + n];
            } else {
                int v = u - 8;
                int wid = v % 7, sgn = (v / 7) & 1, lyr = v / 14;
                const float* Wd = (sgn ? Wd_neg : Wd_pos) + lyr*7168;
                wv = Wd[(wid*32 + krow)*32 + n];
            }
            unsigned short hi = f2bf(wv);
            wG[i4] = (sp == 0) ? (short)hi : (short)f2bf(wv - bf2f(hi));
        }
    }
}

// ---------------------------------------------------------------------------
// Graph kernel v6: batched MFMA, 8 graphs / 256-thread block. (unchanged r9)
// ---------------------------------------------------------------------------
__global__ __launch_bounds__(256) void graph_kernel(
    const float* __restrict__ x0,
    const float* __restrict__ bb_pos, const float* __restrict__ bb_neg,
    const float* __restrict__ bd_pos, const float* __restrict__ bd_neg,
    const short* __restrict__ wG,
    const int* __restrict__ pos_src, const int* __restrict__ pos_dst,
    const int* __restrict__ neg_src, const int* __restrict__ neg_dst,
    float* __restrict__ emb)
{
    __shared__ short U[10240];           // 20480 B
    __shared__ float Yf[5760];           // 23040 B
    __shared__ float Adj[8][4][10][10];  // 12800 B

    const int tid = threadIdx.x;
    const int w   = tid >> 6;
    const int l   = tid & 63;
    const int li  = l & 15;
    const int lk  = l >> 4;
    const int s   = tid >> 7;
    const int rg  = (tid >> 3) & 15;
    const int c4  = tid & 7;
    const int gq  = rg >> 1;
    const int nbase = (rg & 1)*5;

    for (int i = tid; i < 1280; i += 256) {
        int row = i >> 4, kq = i & 15;
        float4 f = ((const float4*)x0)[(size_t)blockIdx.x*1280 + i];
        int k0 = kq*4;
        int ln = (row & 15) + 16*((k0 >> 3) & 3);
        int ki = k0 >> 5, e0 = k0 & 7, mt = row >> 4;
        float vv[4] = {f.x, f.y, f.z, f.w};
        short4v hi4, lo4;
#pragma unroll
        for (int e2 = 0; e2 < 4; ++e2) {
            unsigned short h2 = f2bf(vv[e2]);
            hi4[e2] = (short)h2;
            lo4[e2] = (short)f2bf(vv[e2] - bf2f(h2));
        }
        *(short4v*)&U[AXI(0,mt,ki) + ln*8 + e0] = hi4;
        *(short4v*)&U[AXI(1,mt,ki) + ln*8 + e0] = lo4;
    }

    int*   Ses  = (int*)Yf;
    float* Cm   = Yf + 1280;
    float* Scnt = Yf + 2880;
    for (int i = tid; i < 1280; i += 256) {
        int g = i / 160, r = i % 160, b = r / 40, e = r % 40;
        const int* p = (b==0)?pos_src:(b==1)?pos_dst:(b==2)?neg_src:neg_dst;
        Ses[i] = p[(blockIdx.x*8 + g)*40 + e];
    }
    for (int i = tid; i < 1600; i += 256) Cm[i] = 0.f;
    __syncthreads();
    for (int i = tid; i < 640; i += 256) {
        int g = i / 80, r = i % 80, si = r / 40, e = r % 40;
        int src = Ses[g*160 + (2*si)*40 + e];
        int dst = Ses[g*160 + (2*si+1)*40 + e];
        atomicAdd(&Cm[(g*2 + si)*100 + src*10 + dst], 1.f);
    }
    __syncthreads();
    for (int i = tid; i < 320; i += 256) {
        int g = i / 40, r = i % 40, b = r / 10, n = r % 10;
        int si = b >> 1, isCol = b & 1;
        float ssum = 0.f;
        for (int m = 0; m < 10; ++m)
            ssum += isCol ? Cm[(g*2+si)*100 + m*10 + n] : Cm[(g*2+si)*100 + n*10 + m];
        Scnt[i] = fmaxf(ssum, 1.f);
    }
    __syncthreads();
    for (int i = tid; i < 3200; i += 256) {
        int g = i / 400, r = i % 400, a = r / 100, rr = r % 100;
        int n = rr / 10, m = rr % 10;
        int si = a >> 1, isOut = a & 1;
        float cv = isOut ? Cm[(g*2+si)*100 + m*10 + n] : Cm[(g*2+si)*100 + n*10 + m];
        Adj[g][a][n][m] = cv / Scnt[g*40 + a*10 + n];
    }
    __syncthreads();

    f32x4 acc2[5];

    // base layer
    {
        const float* bb = s ? bb_neg : bb_pos;
        f32x4 b4 = *(const f32x4*)(bb + c4*4);
#pragma unroll
        for (int jj = 0; jj < 5; ++jj) acc2[jj] = b4;
    }
    for (int prod = 0; prod < 2; ++prod) {
        for (int i = 0; i < 5; ++i) {
            int jid = w*5 + i;
            int sgn = (jid >= 10);
            int rem = jid - 10*sgn;
            int nt  = (rem >= 5);
            int mt2 = rem - 5*nt;
            f32x4 cf = {0.f, 0.f, 0.f, 0.f};
            for (int ki = 0; ki < 2; ++ki) {
                short8v ah = *(const short8v*)&U[AXI(0,mt2,ki) + l*8];
                short8v al = *(const short8v*)&U[AXI(1,mt2,ki) + l*8];
                int u = sgn*4 + prod*2 + ki;
                const short* wp = wG + ((((size_t)u*2 + 0)*2 + nt)*64 + l)*8;
                short8v bh = *(const short8v*)wp;
                short8v bl = *(const short8v*)(wp + 1024);
                cf = MFMA16(ah, bh, cf);
                cf = MFMA16(ah, bl, cf);
                cf = MFMA16(al, bh, cf);
            }
#pragma unroll
            for (int r = 0; r < 4; ++r)
                Yf[(sgn*80 + mt2*16 + lk*4 + r)*36 + nt*16 + li] = cf[r];
        }
        __syncthreads();
        if (prod == 0) {
            int a = 2*s;
            for (int m = 0; m < 10; ++m) {
                f32x4 y = *(const f32x4*)&Yf[(s*80 + gq*10 + m)*36 + c4*4];
#pragma unroll
                for (int jj = 0; jj < 5; ++jj)
                    acc2[jj] += Adj[gq][a][nbase+jj][m] * y;
            }
        } else {
#pragma unroll
            for (int jj = 0; jj < 5; ++jj)
                acc2[jj] += *(const f32x4*)&Yf[(s*80 + rg*5 + jj)*36 + c4*4];
        }
        __syncthreads();
    }
#pragma unroll
    for (int jj = 0; jj < 5; ++jj) {
        f32x4 v = acc2[jj];
        float ss = v[0]*v[0] + v[1]*v[1] + v[2]*v[2] + v[3]*v[3];
        ss += __shfl_xor(ss,1); ss += __shfl_xor(ss,2); ss += __shfl_xor(ss,4);
        float rn = 1.f / fmaxf(sqrtf(ss), 1e-12f);
        v *= rn;
        int row = rg*5 + jj;
        int mt2 = row >> 4;
        int k0 = c4*4;
        int ln = (row & 15) + 16*((k0 >> 3) & 3);
        float vv[4] = {v[0], v[1], v[2], v[3]};
        short4v hi4, lo4;
#pragma unroll
        for (int e2 = 0; e2 < 4; ++e2) {
            unsigned short h2 = f2bf(vv[e2]);
            hi4[e2] = (short)h2;
            lo4[e2] = (short)f2bf(vv[e2] - bf2f(h2));
        }
        *(short4v*)&U[AHI(0,s,mt2) + ln*8 + (k0 & 7)] = hi4;
        *(short4v*)&U[AHI(1,s,mt2) + ln*8 + (k0 & 7)] = lo4;
    }
    __syncthreads();

    for (int lyr = 0; lyr < 2; ++lyr) {
        {
            const float* bd = (s ? bd_neg : bd_pos) + lyr*32;
            f32x4 b4 = *(const f32x4*)(bd + c4*4);
#pragma unroll
            for (int jj = 0; jj < 5; ++jj) acc2[jj] = b4;
        }
        for (int b = 0; b < 5; ++b) {
            const int np   = (b == 0 || b == 4) ? 2 : 1;
            const int rel0 = (b == 2 || b == 3) ? 1 : 0;
            const int wid0 = (b == 4) ? 5 : b;
            for (int i = 0; i < 5; ++i) {
                int jid = w*5 + i;
                int sgn = (jid >= 10);
                int rem = jid - 10*sgn;
                int nt  = (rem >= 5);
                int mt2 = rem - 5*nt;
                f32x4 cf = {0.f, 0.f, 0.f, 0.f};
                {
                    int wh = sgn ^ rel0;
                    int u = 8 + (lyr*2 + sgn)*7 + wid0;
                    short8v ah = *(const short8v*)&U[AHI(0,wh,mt2) + l*8];
                    short8v al = *(const short8v*)&U[AHI(1,wh,mt2) + l*8];
                    const short* wp = wG + ((((size_t)u*2 + 0)*2 + nt)*64 + l)*8;
                    short8v bh = *(const short8v*)wp;
                    short8v bl = *(const short8v*)(wp + 1024);
                    cf = MFMA16(ah, bh, cf);
                    cf = MFMA16(ah, bl, cf);
                    cf = MFMA16(al, bh, cf);
                }
                if (np == 2) {
                    int wid1 = (b == 0) ? 4 : 6;
                    int wh = sgn ^ 1;
                    int u = 8 + (lyr*2 + sgn)*7 + wid1;
                    short8v ah = *(const short8v*)&U[AHI(0,wh,mt2) + l*8];
                    short8v al = *(const short8v*)&U[AHI(1,wh,mt2) + l*8];
                    const short* wp = wG + ((((size_t)u*2 + 0)*2 + nt)*64 + l)*8;
                    short8v bh = *(const short8v*)wp;
                    short8v bl = *(const short8v*)(wp + 1024);
                    cf = MFMA16(ah, bh, cf);
                    cf = MFMA16(ah, bl, cf);
                    cf = MFMA16(al, bh, cf);
                }
#pragma unroll
                for (int r = 0; r < 4; ++r)
                    Yf[(sgn*80 + mt2*16 + lk*4 + r)*36 + nt*16 + li] = cf[r];
            }
            __syncthreads();
            if (b < 4) {
                int a = (b == 0) ? 2*s : (b == 1) ? 2*s + 1 : (b == 2) ? 2 - 2*s : 3 - 2*s;
                for (int m = 0; m < 10; ++m) {
                    f32x4 y = *(const f32x4*)&Yf[(s*80 + gq*10 + m)*36 + c4*4];
#pragma unroll
                    for (int jj = 0; jj < 5; ++jj)
                        acc2[jj] += Adj[gq][a][nbase+jj][m] * y;
                }
            } else {
#pragma unroll
                for (int jj = 0; jj < 5; ++jj)
                    acc2[jj] += *(const f32x4*)&Yf[(s*80 + rg*5 + jj)*36 + c4*4];
            }
            __syncthreads();
        }
#pragma unroll
        for (int jj = 0; jj < 5; ++jj) {
            f32x4 v = acc2[jj];
            float ss = v[0]*v[0] + v[1]*v[1] + v[2]*v[2] + v[3]*v[3];
            ss += __shfl_xor(ss,1); ss += __shfl_xor(ss,2); ss += __shfl_xor(ss,4);
            float rn = 1.f / fmaxf(sqrtf(ss), 1e-12f);
            v *= rn;
            int row = rg*5 + jj;
            if (lyr == 0) {
                int mt2 = row >> 4;
                int k0 = c4*4;
                int ln = (row & 15) + 16*((k0 >> 3) & 3);
                float vv[4] = {v[0], v[1], v[2], v[3]};
                short4v hi4, lo4;
#pragma unroll
                for (int e2 = 0; e2 < 4; ++e2) {
                    unsigned short h2 = f2bf(vv[e2]);
                    hi4[e2] = (short)h2;
                    lo4[e2] = (short)f2bf(vv[e2] - bf2f(h2));
                }
                *(short4v*)&U[AHI(0,s,mt2) + ln*8 + (k0 & 7)] = hi4;
                *(short4v*)&U[AHI(1,s,mt2) + ln*8 + (k0 & 7)] = lo4;
            } else {
                *(f32x4*)&emb[((size_t)(blockIdx.x*80 + row))*64 + s*32 + c4*4] = v;
            }
        }
        __syncthreads();
    }
}

// ---------------------------------------------------------------------------
// Persistent MFMA LSTM v2: 3-buffer register prefetch of B (2 ki ahead,
// rolling across the t boundary) + early issue of next-step emb/add/wadd.
// ---------------------------------------------------------------------------
#define LOADB(pt, pki, BH, BL)                                                 \
    {                                                                          \
        const short* wtp = wB + (size_t)(pt) * WB_PER_T;                       \
        _Pragma("unroll")                                                      \
        for (int g = 0; g < 4; ++g) {                                          \
            int nt = w + 8*g;                                                  \
            BH[g] = *(const short8v*)(wtp + (((size_t)(pki)*32 + nt)*64 + l)*8);      \
            BL[g] = *(const short8v*)(wtp + (((size_t)(6+(pki))*32 + nt)*64 + l)*8);  \
        }                                                                      \
    }

#define KI_STEP(ki, CH, CL, pt, pki, PH, PL)                                   \
    {                                                                          \
        short8v ah0 = *(const short8v*)&aP[AIDX(0,ki,0,l)];                    \
        short8v ah1 = *(const short8v*)&aP[AIDX(0,ki,1,l)];                    \
        short8v al0 = *(const short8v*)&aP[AIDX(1,ki,0,l)];                    \
        short8v al1 = *(const short8v*)&aP[AIDX(1,ki,1,l)];                    \
        LOADB(pt, pki, PH, PL)                                                 \
        _Pragma("unroll")                                                      \
        for (int g = 0; g < 4; ++g) {                                          \
            acc[0][g] = MFMA16(ah0, CH[g], acc[0][g]);                         \
            acc[0][g] = MFMA16(ah0, CL[g], acc[0][g]);                         \
            acc[0][g] = MFMA16(al0, CH[g], acc[0][g]);                         \
            acc[1][g] = MFMA16(ah1, CH[g], acc[1][g]);                         \
            acc[1][g] = MFMA16(ah1, CL[g], acc[1][g]);                         \
            acc[1][g] = MFMA16(al1, CH[g], acc[1][g]);                         \
        }                                                                      \
    }

__global__ __launch_bounds__(512) void lstm_mfma(
    const float* __restrict__ emb, const float* __restrict__ add_info,
    const short* __restrict__ wB, const float* __restrict__ wadd,
    const float* __restrict__ bsum, const float* __restrict__ hx0,
    const float* __restrict__ cx0, float* __restrict__ hbuf)
{
    __shared__ short aP[12288];          // [2][6][2][64][8] bf16 bits, 24.6 KB
    __shared__ float Sadd[2][32][2];
    const int tid = threadIdx.x;
    const int w  = tid >> 6;             // wave 0..7
    const int l  = tid & 63;
    const int li = l & 15;
    const int lk = l >> 4;
    const int R0 = blockIdx.x * 32;

    {
        int row = tid >> 4, j0 = (tid & 15) * 8;
        const float* hp = hx0 + (size_t)(R0 + row)*128 + j0;
        float4 h0 = *(const float4*)hp;
        float4 h1 = *(const float4*)(hp + 4);
        float v[8] = {h0.x,h0.y,h0.z,h0.w,h1.x,h1.y,h1.z,h1.w};
        short8v hi, lo;
#pragma unroll
        for (int e = 0; e < 8; ++e) {
            unsigned short hs = f2bf(v[e]);
            hi[e] = (short)hs;
            lo[e] = (short)f2bf(v[e] - bf2f(hs));
        }
        int mt = row >> 4, ln = (row & 15) + 16*((j0 >> 3) & 3), ki = j0 >> 5;
        *(short8v*)&aP[AIDX(0,ki,mt,ln)] = hi;
        *(short8v*)&aP[AIDX(1,ki,mt,ln)] = lo;
    }
    {
        int row = tid >> 4, d0 = (tid & 15)*4;
        int R = R0 + row, g = R/10, p = R - 10*g;
        float4 f = *(const float4*)&emb[((size_t)(g*TT + 0)*PP + p)*64 + d0];
        int k0 = 128 + d0;
        int mt = row>>4, ln = (row&15) + 16*((k0>>3)&3), ki = k0>>5, e0 = k0&7;
        float v[4] = {f.x,f.y,f.z,f.w};
        short4v hi, lo;
#pragma unroll
        for (int e = 0; e < 4; ++e) {
            unsigned short hs = f2bf(v[e]);
            hi[e] = (short)hs;
            lo[e] = (short)f2bf(v[e] - bf2f(hs));
        }
        *(short4v*)&aP[AIDX(0,ki,mt,ln)+e0] = hi;
        *(short4v*)&aP[AIDX(1,ki,mt,ln)+e0] = lo;
    }
    if (tid < 64) {
        int row = tid >> 1, cc = tid & 1;
        int R = R0 + row, g = R/10, p = R - 10*g;
        Sadd[0][row][cc] = add_info[((size_t)(g*MM + 0)*PP + p)*2 + cc];
    }
    float c[2][4];
#pragma unroll
    for (int mt = 0; mt < 2; ++mt)
#pragma unroll
        for (int r = 0; r < 4; ++r) {
            int row = mt*16 + lk*4 + r;
            c[mt][r] = cx0[(size_t)(R0+row)*128 + 16*w + li];
        }

    // B prefetch pipeline: b0 = (0,ki0), b1 = (0,ki1)
    short8v b0h[4], b0l[4], b1h[4], b1l[4], b2h[4], b2l[4];
    LOADB(0, 0, b0h, b0l)
    LOADB(0, 1, b1h, b1l)
    __syncthreads();

    for (int t = 0; t < TT; ++t) {
        const int tn = (t < TT-1) ? t+1 : t;
        // early-issue next-step inputs (consumed after barrier in epilogue)
        float4 fnext;
        {
            int row = tid >> 4, d0 = (tid & 15)*4;
            int R = R0 + row, g = R/10, p = R - 10*g;
            fnext = *(const float4*)&emb[((size_t)(g*TT + tn)*PP + p)*64 + d0];
        }
        float adn0 = 0.f, adn1 = 0.f;
        if (tid < 64) {
            int rw = tid >> 1, cc = tid & 1;
            int R2 = R0 + rw, g2 = R2/10, p2 = R2 - 10*g2;
            adn0 = add_info[((size_t)(g2*MM + tn/MM)*PP + p2)*2 + cc];
            (void)adn1;
        }
        float wa0[4], wa1[4];
#pragma unroll
        for (int g = 0; g < 4; ++g) {
            wa0[g] = wadd[(size_t)(t*2+0)*512 + 128*g + 16*w + li];
            wa1[g] = wadd[(size_t)(t*2+1)*512 + 128*g + 16*w + li];
        }

        f32x4 acc[2][4];
#pragma unroll
        for (int g = 0; g < 4; ++g) {
            float bs = bsum[t*512 + 128*g + 16*w + li];
            acc[0][g] = (f32x4){bs,bs,bs,bs};
            acc[1][g] = (f32x4){bs,bs,bs,bs};
        }

        KI_STEP(0, b0h, b0l, t,  2, b2h, b2l)
        KI_STEP(1, b1h, b1l, t,  3, b0h, b0l)
        KI_STEP(2, b2h, b2l, t,  4, b1h, b1l)
        KI_STEP(3, b0h, b0l, t,  5, b2h, b2l)
        KI_STEP(4, b1h, b1l, tn, 0, b0h, b0l)
        KI_STEP(5, b2h, b2l, tn, 1, b1h, b1l)
        __syncthreads();   // all aP reads done

        const int sb = t & 1;
        const int j  = 16*w + li;
        const int jsh = 16*((j >> 3) & 3);
        const int jki = j >> 5;
        const int je  = j & 7;
#pragma unroll
        for (int mt = 0; mt < 2; ++mt) {
#pragma unroll
            for (int r = 0; r < 4; ++r) {
                int row = mt*16 + lk*4 + r;
                float ad0 = Sadd[sb][row][0], ad1 = Sadd[sb][row][1];
                float v0 = acc[mt][0][r] + ad0*wa0[0] + ad1*wa1[0];
                float v1 = acc[mt][1][r] + ad0*wa0[1] + ad1*wa1[1];
                float v2 = acc[mt][2][r] + ad0*wa0[2] + ad1*wa1[2];
                float v3 = acc[mt][3][r] + ad0*wa0[3] + ad1*wa1[3];
                float iv = sigm(v0);
                float fv = sigm(v1);
                float gv = tanh_fast(v2);
                float ov = sigm(v3);
                float cn = fv*c[mt][r] + iv*gv;
                c[mt][r] = cn;
                float hv = ov*tanh_fast(cn);
                unsigned short hs = f2bf(hv);
                int ln = (row & 15) + jsh;
                aP[AIDX(0, jki, mt, ln) + je] = (short)hs;
                aP[AIDX(1, jki, mt, ln) + je] = (short)f2bf(hv - bf2f(hs));
                if (t == TT-1) hbuf[(size_t)(R0+row)*128 + j] = hv;
            }
        }
        if (t < TT-1) {
            int row = tid >> 4, d0 = (tid & 15)*4;
            int k0 = 128 + d0;
            int mt = row>>4, ln = (row&15) + 16*((k0>>3)&3), ki = k0>>5, e0 = k0&7;
            float v[4] = {fnext.x, fnext.y, fnext.z, fnext.w};
            short4v hi, lo;
#pragma unroll
            for (int e = 0; e < 4; ++e) {
                unsigned short hs = f2bf(v[e]);
                hi[e] = (short)hs;
                lo[e] = (short)f2bf(v[e] - bf2f(hs));
            }
            *(short4v*)&aP[AIDX(0,ki,mt,ln)+e0] = hi;
            *(short4v*)&aP[AIDX(1,ki,mt,ln)+e0] = lo;
            if (tid < 64) {
                int rw = tid >> 1, cc = tid & 1;
                Sadd[sb^1][rw][cc] = adn0;
            }
        }
        __syncthreads();
    }
}

// ---------------------------------------------------------------------------
// Final projection: out = h_last @ Wf + bf
// ---------------------------------------------------------------------------
__global__ __launch_bounds__(256) void final_proj(
    const float* __restrict__ hbuf, const float* __restrict__ Wf,
    const float* __restrict__ bf, float* __restrict__ out)
{
    __shared__ float wl[128*32];
    __shared__ float hl[64][128];
    const int tid = threadIdx.x;
    const int row0 = blockIdx.x * 64;
    for (int i = tid; i < 4096; i += 256) wl[i] = Wf[i];
    for (int i = tid; i < 8192; i += 256) hl[i>>7][i&127] = hbuf[row0*128 + i];
    __syncthreads();
    const int e  = tid & 31;
    const int rg = tid >> 5;
    float b = bf[e];
    float acc[8];
#pragma unroll
    for (int r=0;r<8;++r) acc[r] = b;
    for (int k = 0; k < 128; ++k) {
        float ww = wl[k*32 + e];
#pragma unroll
        for (int r=0;r<8;++r) acc[r] += hl[rg*8+r][k]*ww;
    }
#pragma unroll
    for (int r=0;r<8;++r) out[(row0 + rg*8 + r)*32 + e] = acc[r];
}

// ---------------------------------------------------------------------------
extern "C" void kernel_launch(void* const* d_in, const int* in_sizes, int n_in,
                              void* d_out, int out_size, void* d_ws, size_t ws_size,
                              hipStream_t stream)
{
    const float* x0       = (const float*)d_in[0];
    const float* add_info = (const float*)d_in[1];
    const float* Wb_pos   = (const float*)d_in[2];
    const float* bb_pos   = (const float*)d_in[3];
    const float* Wb_neg   = (const float*)d_in[4];
    const float* bb_neg   = (const float*)d_in[5];
    const float* Wd_pos   = (const float*)d_in[6];
    const float* bd_pos   = (const float*)d_in[7];
    const float* Wd_neg   = (const float*)d_in[8];
    const float* bd_neg   = (const float*)d_in[9];
    const float* W_ih     = (const float*)d_in[10];
    const float* W_hh     = (const float*)d_in[11];
    const float* b_ih     = (const float*)d_in[12];
    const float* b_hh     = (const float*)d_in[13];
    const float* hx0      = (const float*)d_in[14];
    const float* cx0      = (const float*)d_in[15];
    const float* Wf       = (const float*)d_in[16];
    const float* bf       = (const float*)d_in[17];
    const int*   pos_src  = (const int*)d_in[18];
    const int*   pos_dst  = (const int*)d_in[19];
    const int*   neg_src  = (const int*)d_in[20];
    const int*   neg_dst  = (const int*)d_in[21];

    float* ws    = (float*)d_ws;
    float* emb   = ws;                        // 8,192,000 f32
    float* hbuf  = emb   + 8192000;           //   655,360 f32
    float* bsumw = hbuf  + 655360;            //    12,800 f32
    float* waddw = bsumw + 12800;             //    25,600 f32
    short* wBw   = (short*)(waddw + 25600);   // 4,915,200 shorts
    short* wGw   = wBw + 4915200;             //    73,728 shorts (~45.6 MiB total)

    hipLaunchKernelGGL(prep_kernel, dim3(2048), dim3(256), 0, stream,
                       W_ih, W_hh, b_ih, b_hh, Wb_pos, Wb_neg, Wd_pos, Wd_neg,
                       wBw, waddw, bsumw, wGw);
    hipLaunchKernelGGL(graph_kernel, dim3(NGRAPH/8), dim3(256), 0, stream,
                       x0, bb_pos, bb_neg, bd_pos, bd_neg, wGw,
                       pos_src, pos_dst, neg_src, neg_dst, emb);
    hipLaunchKernelGGL(lstm_mfma, dim3(160), dim3(512), 0, stream,
                       emb, add_info, wBw, waddw, bsumw, hx0, cx0, hbuf);
    hipLaunchKernelGGL(final_proj, dim3(80), dim3(256), 0, stream,
                       hbuf, Wf, bf, (float*)d_out);
}

// Round 11
// 378.125 us; speedup vs baseline: 2.9732x; 1.0519x over previous
//
#include <hip/hip_runtime.h>
#include <math.h>

#define GG 512
#define TT 25
#define PP 10
#define MM 5
#define EE 32
#define HID 32
#define HH 128
#define NEDGE 40
#define NGRAPH (GG*TT)          // 12800
#define NTOT (GG*TT*PP)         // 128000

typedef __attribute__((ext_vector_type(8))) short short8v;
typedef __attribute__((ext_vector_type(4))) short short4v;
typedef __attribute__((ext_vector_type(4))) float f32x4;

// lstm A-panel LDS index: [s][ki<6][mt<2][lane<64][e<8] (shorts)
#define AIDX(s,ki,mt,l) (((((s)*6+(ki))*2+(mt))*64+(l))*8)
#define WB_PER_T 196608   // 2*6*32*64*8

// graph A-panel indices within U[10240] shorts (layouts used at disjoint times)
#define AXI(sp,mt,ki) ((((sp)*5+(mt))*2+(ki))*512)
#define AHI(sp,wh,mt) ((((sp)*2+(wh))*5+(mt))*512)
#define NWG 73728         // 36 units * 2(sp) * 2(nt) * 64 * 8

#define MFMA16(a,b,c) __builtin_amdgcn_mfma_f32_16x16x32_bf16(a,b,c,0,0,0)

__device__ __forceinline__ unsigned short f2bf(float x){
    unsigned u = __float_as_uint(x);
    u += 0x7fffu + ((u >> 16) & 1u);
    return (unsigned short)(u >> 16);
}
__device__ __forceinline__ float bf2f(unsigned short s){
    return __uint_as_float(((unsigned)s) << 16);
}
__device__ __forceinline__ float sigm(float x){ return 1.f/(1.f+__expf(-x)); }
__device__ __forceinline__ float tanh_fast(float x){
    float ax = fabsf(x);
    float e  = __expf(-2.f*ax);
    float t  = (1.f-e)/(1.f+e);
    return copysignf(t, x);
}

// ---------------------------------------------------------------------------
// Prep: LSTM weight frags + graph-GEMM B-fragments wG. (unchanged from r9)
// ---------------------------------------------------------------------------
__global__ void prep_kernel(const float* __restrict__ W_ih, const float* __restrict__ W_hh,
                            const float* __restrict__ b_ih, const float* __restrict__ b_hh,
                            const float* __restrict__ Wb_pos, const float* __restrict__ Wb_neg,
                            const float* __restrict__ Wd_pos, const float* __restrict__ Wd_neg,
                            short* __restrict__ wB, float* __restrict__ wadd,
                            float* __restrict__ bsum, short* __restrict__ wG)
{
    const int NW = TT*WB_PER_T;          // 4,915,200
    const int NA = TT*2*512;             // 25,600
    const int NB = TT*512;               // 12,800
    const int total = NW + NA + NB + NWG;
    for (int idx = blockIdx.x*blockDim.x + threadIdx.x; idx < total;
         idx += gridDim.x*blockDim.x) {
        if (idx < NW) {
            int e  = idx & 7;
            int l  = (idx >> 3) & 63;
            int nt = (idx >> 9) & 31;
            int rest = idx >> 14;        // (t*2+s)*6 + ki
            int ki = rest % 6; rest /= 6;
            int s  = rest & 1;
            int t  = rest >> 1;
            int k  = ki*32 + (l >> 4)*8 + e;
            int n  = nt*16 + (l & 15);
            float wv = (k < 128) ? W_hh[(size_t)(t*512 + n)*128 + k]
                                 : W_ih[(size_t)(t*512 + n)*66 + (k - 128)];
            unsigned short hi = f2bf(wv);
            unsigned short outv = (s == 0) ? hi : f2bf(wv - bf2f(hi));
            wB[idx] = (short)outv;
        } else if (idx < NW + NA) {
            int i2 = idx - NW;
            int t = i2 / 1024, r = i2 % 1024;
            int cc = r >> 9, n = r & 511;
            wadd[i2] = W_ih[(size_t)(t*512 + n)*66 + 64 + cc];
        } else if (idx < NW + NA + NB) {
            int i3 = idx - NW - NA;
            bsum[i3] = b_ih[i3] + b_hh[i3];
        } else {
            int i4 = idx - NW - NA - NB;     // < 73728
            int e  = i4 & 7;
            int ll = (i4 >> 3) & 63;
            int nt = (i4 >> 9) & 1;
            int sp = (i4 >> 10) & 1;
            int u  = i4 >> 11;               // 0..35
            int n  = nt*16 + (ll & 15);
            int krow = (ll >> 4)*8 + e;
            float wv;
            if (u < 8) {
                int sgn = u >> 2, prod = (u >> 1) & 1, ki = u & 1;
                const float* Wb = sgn ? Wb_neg : Wb_pos;
                wv = Wb[(prod*64 + ki*32 + krow)*32 + n];
            } else {
                int v = u - 8;
                int wid = v % 7, sgn = (v / 7) & 1, lyr = v / 14;
                const float* Wd = (sgn ? Wd_neg : Wd_pos) + lyr*7168;
                wv = Wd[(wid*32 + krow)*32 + n];
            }
            unsigned short hi = f2bf(wv);
            wG[i4] = (sp == 0) ? (short)hi : (short)f2bf(wv - bf2f(hi));
        }
    }
}

// ---------------------------------------------------------------------------
// Graph kernel v7: batched MFMA with pipelined buckets. 8 graphs / 256 thr.
// Double-buffered Yf, ONE barrier per bucket; bucket b+1's MFMAs are issued
// before bucket b's barrier+apply so load/MFMA latency hides under VALU.
// ---------------------------------------------------------------------------
__global__ __launch_bounds__(256) void graph_kernel(
    const float* __restrict__ x0,
    const float* __restrict__ bb_pos, const float* __restrict__ bb_neg,
    const float* __restrict__ bd_pos, const float* __restrict__ bd_neg,
    const short* __restrict__ wG,
    const int* __restrict__ pos_src, const int* __restrict__ pos_dst,
    const int* __restrict__ neg_src, const int* __restrict__ neg_dst,
    float* __restrict__ emb)
{
    __shared__ short U[10240];           // 20480 B: AX frags, then AH frags
    __shared__ float Yf[2][5760];        // 46080 B double-buffered [2sgn*80][36]
    __shared__ float Adj[8][4][10][10];  // 12800 B   total 79360 B

    const int tid = threadIdx.x;
    const int w   = tid >> 6;
    const int l   = tid & 63;
    const int li  = l & 15;
    const int lk  = l >> 4;
    const int s   = tid >> 7;            // output sign this thread owns
    const int rg  = (tid >> 3) & 15;     // row group (5 rows)
    const int c4  = tid & 7;             // 4-col group
    const int gq  = rg >> 1;             // graph (block-local)
    const int nbase = (rg & 1)*5;        // node base within graph

    // ---- stage x0 -> AX fragments (hi/lo bf16) ----
    for (int i = tid; i < 1280; i += 256) {
        int row = i >> 4, kq = i & 15;
        float4 f = ((const float4*)x0)[(size_t)blockIdx.x*1280 + i];
        int k0 = kq*4;
        int ln = (row & 15) + 16*((k0 >> 3) & 3);
        int ki = k0 >> 5, e0 = k0 & 7, mt = row >> 4;
        float vv[4] = {f.x, f.y, f.z, f.w};
        short4v hi4, lo4;
#pragma unroll
        for (int e2 = 0; e2 < 4; ++e2) {
            unsigned short h2 = f2bf(vv[e2]);
            hi4[e2] = (short)h2;
            lo4[e2] = (short)f2bf(vv[e2] - bf2f(h2));
        }
        *(short4v*)&U[AXI(0,mt,ki) + ln*8 + e0] = hi4;
        *(short4v*)&U[AXI(1,mt,ki) + ln*8 + e0] = lo4;
    }

    // ---- edges / counts / adjacency (overlaid in Yf[0], dead later) ----
    int*   Ses  = (int*)&Yf[0][0];       // [8][4][40] = 1280
    float* Cm   = &Yf[0][0] + 1280;      // [8][2][100] = 1600
    float* Scnt = &Yf[0][0] + 2880;      // [8][4][10]  = 320
    for (int i = tid; i < 1280; i += 256) {
        int g = i / 160, r = i % 160, b = r / 40, e = r % 40;
        const int* p = (b==0)?pos_src:(b==1)?pos_dst:(b==2)?neg_src:neg_dst;
        Ses[i] = p[(blockIdx.x*8 + g)*40 + e];
    }
    for (int i = tid; i < 1600; i += 256) Cm[i] = 0.f;
    __syncthreads();
    for (int i = tid; i < 640; i += 256) {
        int g = i / 80, r = i % 80, si = r / 40, e = r % 40;
        int src = Ses[g*160 + (2*si)*40 + e];
        int dst = Ses[g*160 + (2*si+1)*40 + e];
        atomicAdd(&Cm[(g*2 + si)*100 + src*10 + dst], 1.f);
    }
    __syncthreads();
    for (int i = tid; i < 320; i += 256) {
        int g = i / 40, r = i % 40, b = r / 10, n = r % 10;
        int si = b >> 1, isCol = b & 1;
        float ssum = 0.f;
        for (int m = 0; m < 10; ++m)
            ssum += isCol ? Cm[(g*2+si)*100 + m*10 + n] : Cm[(g*2+si)*100 + n*10 + m];
        Scnt[i] = fmaxf(ssum, 1.f);
    }
    __syncthreads();
    for (int i = tid; i < 3200; i += 256) {
        int g = i / 400, r = i % 400, a = r / 100, rr = r % 100;
        int n = rr / 10, m = rr % 10;
        int si = a >> 1, isOut = a & 1;
        float cv = isOut ? Cm[(g*2+si)*100 + m*10 + n] : Cm[(g*2+si)*100 + n*10 + m];
        Adj[g][a][n][m] = cv / Scnt[g*40 + a*10 + n];
    }
    __syncthreads();   // Adj ready; Yf free

    // ---- bucket machinery ----
#define JDECOMP(i) \
        int jid = w*5 + (i); \
        int sgn = (jid >= 10); \
        int rem = jid - 10*sgn; \
        int nt  = (rem >= 5); \
        int mt2 = rem - 5*nt;

#define BASE_BUCKET(prod, CF) \
    _Pragma("unroll") \
    for (int i = 0; i < 5; ++i) { \
        JDECOMP(i) \
        f32x4 cf = {0.f,0.f,0.f,0.f}; \
        _Pragma("unroll") \
        for (int ki = 0; ki < 2; ++ki) { \
            short8v ah = *(const short8v*)&U[AXI(0,mt2,ki) + l*8]; \
            short8v al = *(const short8v*)&U[AXI(1,mt2,ki) + l*8]; \
            int u = sgn*4 + (prod)*2 + ki; \
            const short* wp = wG + ((((size_t)u*2)*2 + nt)*64 + l)*8; \
            short8v bh = *(const short8v*)wp; \
            short8v bl = *(const short8v*)(wp + 1024); \
            cf = MFMA16(ah, bh, cf); \
            cf = MFMA16(ah, bl, cf); \
            cf = MFMA16(al, bh, cf); \
        } \
        CF[i] = cf; \
    }

#define DEEP_BUCKET(lyr, q, CF) \
    _Pragma("unroll") \
    for (int i = 0; i < 5; ++i) { \
        JDECOMP(i) \
        f32x4 cf = {0.f,0.f,0.f,0.f}; \
        { \
            const int wid0 = ((q) == 4) ? 5 : (q); \
            const int rel0 = ((q) == 2 || (q) == 3) ? 1 : 0; \
            int wh = sgn ^ rel0; \
            int u = 8 + ((lyr)*2 + sgn)*7 + wid0; \
            short8v ah = *(const short8v*)&U[AHI(0,wh,mt2) + l*8]; \
            short8v al = *(const short8v*)&U[AHI(1,wh,mt2) + l*8]; \
            const short* wp = wG + ((((size_t)u*2)*2 + nt)*64 + l)*8; \
            short8v bh = *(const short8v*)wp; \
            short8v bl = *(const short8v*)(wp + 1024); \
            cf = MFMA16(ah, bh, cf); \
            cf = MFMA16(ah, bl, cf); \
            cf = MFMA16(al, bh, cf); \
        } \
        if ((q) == 0 || (q) == 4) { \
            const int wid1 = ((q) == 0) ? 4 : 6; \
            int wh = sgn ^ 1; \
            int u = 8 + ((lyr)*2 + sgn)*7 + wid1; \
            short8v ah = *(const short8v*)&U[AHI(0,wh,mt2) + l*8]; \
            short8v al = *(const short8v*)&U[AHI(1,wh,mt2) + l*8]; \
            const short* wp = wG + ((((size_t)u*2)*2 + nt)*64 + l)*8; \
            short8v bh = *(const short8v*)wp; \
            short8v bl = *(const short8v*)(wp + 1024); \
            cf = MFMA16(ah, bh, cf); \
            cf = MFMA16(ah, bl, cf); \
            cf = MFMA16(al, bh, cf); \
        } \
        CF[i] = cf; \
    }

#define STORE_CF(CF, buf) \
    _Pragma("unroll") \
    for (int i = 0; i < 5; ++i) { \
        JDECOMP(i) \
        _Pragma("unroll") \
        for (int r = 0; r < 4; ++r) \
            Yf[buf][(sgn*80 + mt2*16 + lk*4 + r)*36 + nt*16 + li] = CF[i][r]; \
    }

#define APPLY_ADJ(aIdx, buf) \
    _Pragma("unroll") \
    for (int m = 0; m < 10; ++m) { \
        f32x4 y = *(const f32x4*)&Yf[buf][(s*80 + gq*10 + m)*36 + c4*4]; \
        _Pragma("unroll") \
        for (int jj = 0; jj < 5; ++jj) \
            acc2[jj] += Adj[gq][aIdx][nbase+jj][m] * y; \
    }

#define APPLY_SELF(buf) \
    _Pragma("unroll") \
    for (int jj = 0; jj < 5; ++jj) \
        acc2[jj] += *(const f32x4*)&Yf[buf][(s*80 + rg*5 + jj)*36 + c4*4];

    f32x4 acc2[5];
    f32x4 cfA[5], cfB[5];

    // =================== base layer (pipelined, 3 barriers) ===================
    {
        const float* bb = s ? bb_neg : bb_pos;
        f32x4 b4 = *(const f32x4*)(bb + c4*4);
#pragma unroll
        for (int jj = 0; jj < 5; ++jj) acc2[jj] = b4;
    }
    BASE_BUCKET(0, cfA)          // mean product
    STORE_CF(cfA, 0)
    BASE_BUCKET(1, cfB)          // self product (issued early)
    __syncthreads();             // Yf[0] ready
    APPLY_ADJ(2*s, 0)
    STORE_CF(cfB, 1)
    __syncthreads();             // Yf[1] ready
    APPLY_SELF(1)
    // epilogue: l2norm -> AH frags
#pragma unroll
    for (int jj = 0; jj < 5; ++jj) {
        f32x4 v = acc2[jj];
        float ss = v[0]*v[0] + v[1]*v[1] + v[2]*v[2] + v[3]*v[3];
        ss += __shfl_xor(ss,1); ss += __shfl_xor(ss,2); ss += __shfl_xor(ss,4);
        float rn = 1.f / fmaxf(sqrtf(ss), 1e-12f);
        v *= rn;
        int row = rg*5 + jj;
        int mt2 = row >> 4;
        int k0 = c4*4;
        int ln = (row & 15) + 16*((k0 >> 3) & 3);
        float vv[4] = {v[0], v[1], v[2], v[3]};
        short4v hi4, lo4;
#pragma unroll
        for (int e2 = 0; e2 < 4; ++e2) {
            unsigned short h2 = f2bf(vv[e2]);
            hi4[e2] = (short)h2;
            lo4[e2] = (short)f2bf(vv[e2] - bf2f(h2));
        }
        *(short4v*)&U[AHI(0,s,mt2) + ln*8 + (k0 & 7)] = hi4;
        *(short4v*)&U[AHI(1,s,mt2) + ln*8 + (k0 & 7)] = lo4;
    }
    __syncthreads();             // AH visible; Yf free

    // =================== two deep layers (pipelined, 6 barriers each) =========
    for (int lyr = 0; lyr < 2; ++lyr) {
        {
            const float* bd = (s ? bd_neg : bd_pos) + lyr*32;
            f32x4 b4 = *(const f32x4*)(bd + c4*4);
#pragma unroll
            for (int jj = 0; jj < 5; ++jj) acc2[jj] = b4;
        }
        DEEP_BUCKET(lyr, 0, cfA)
        STORE_CF(cfA, 0)
        DEEP_BUCKET(lyr, 1, cfB)     // issue b1 early
        __syncthreads();             // Yf[0] ready
        APPLY_ADJ(2*s, 0)
        STORE_CF(cfB, 1)
        DEEP_BUCKET(lyr, 2, cfA)     // issue b2 early
        __syncthreads();             // Yf[1] ready
        APPLY_ADJ(2*s+1, 1)
        STORE_CF(cfA, 0)
        DEEP_BUCKET(lyr, 3, cfB)     // issue b3 early
        __syncthreads();             // Yf[0] ready
        APPLY_ADJ(2-2*s, 0)
        STORE_CF(cfB, 1)
        DEEP_BUCKET(lyr, 4, cfA)     // issue b4 (self) early
        __syncthreads();             // Yf[1] ready
        APPLY_ADJ(3-2*s, 1)
        STORE_CF(cfA, 0)
        __syncthreads();             // Yf[0] ready
        APPLY_SELF(0)
        // epilogue: l2norm; write AH (lyr 0) or emb (lyr 1)
#pragma unroll
        for (int jj = 0; jj < 5; ++jj) {
            f32x4 v = acc2[jj];
            float ss = v[0]*v[0] + v[1]*v[1] + v[2]*v[2] + v[3]*v[3];
            ss += __shfl_xor(ss,1); ss += __shfl_xor(ss,2); ss += __shfl_xor(ss,4);
            float rn = 1.f / fmaxf(sqrtf(ss), 1e-12f);
            v *= rn;
            int row = rg*5 + jj;
            if (lyr == 0) {
                int mt2 = row >> 4;
                int k0 = c4*4;
                int ln = (row & 15) + 16*((k0 >> 3) & 3);
                float vv[4] = {v[0], v[1], v[2], v[3]};
                short4v hi4, lo4;
#pragma unroll
                for (int e2 = 0; e2 < 4; ++e2) {
                    unsigned short h2 = f2bf(vv[e2]);
                    hi4[e2] = (short)h2;
                    lo4[e2] = (short)f2bf(vv[e2] - bf2f(h2));
                }
                *(short4v*)&U[AHI(0,s,mt2) + ln*8 + (k0 & 7)] = hi4;
                *(short4v*)&U[AHI(1,s,mt2) + ln*8 + (k0 & 7)] = lo4;
            } else {
                *(f32x4*)&emb[((size_t)(blockIdx.x*80 + row))*64 + s*32 + c4*4] = v;
            }
        }
        __syncthreads();             // AH visible; Yf free for next layer
    }
}

// ---------------------------------------------------------------------------
// Persistent MFMA LSTM v2 (unchanged from r10 — known good).
// ---------------------------------------------------------------------------
#define LOADB(pt, pki, BH, BL)                                                 \
    {                                                                          \
        const short* wtp = wB + (size_t)(pt) * WB_PER_T;                       \
        _Pragma("unroll")                                                      \
        for (int g = 0; g < 4; ++g) {                                          \
            int nt = w + 8*g;                                                  \
            BH[g] = *(const short8v*)(wtp + (((size_t)(pki)*32 + nt)*64 + l)*8);      \
            BL[g] = *(const short8v*)(wtp + (((size_t)(6+(pki))*32 + nt)*64 + l)*8);  \
        }                                                                      \
    }

#define KI_STEP(ki, CH, CL, pt, pki, PH, PL)                                   \
    {                                                                          \
        short8v ah0 = *(const short8v*)&aP[AIDX(0,ki,0,l)];                    \
        short8v ah1 = *(const short8v*)&aP[AIDX(0,ki,1,l)];                    \
        short8v al0 = *(const short8v*)&aP[AIDX(1,ki,0,l)];                    \
        short8v al1 = *(const short8v*)&aP[AIDX(1,ki,1,l)];                    \
        LOADB(pt, pki, PH, PL)                                                 \
        _Pragma("unroll")                                                      \
        for (int g = 0; g < 4; ++g) {                                          \
            acc[0][g] = MFMA16(ah0, CH[g], acc[0][g]);                         \
            acc[0][g] = MFMA16(ah0, CL[g], acc[0][g]);                         \
            acc[0][g] = MFMA16(al0, CH[g], acc[0][g]);                         \
            acc[1][g] = MFMA16(ah1, CH[g], acc[1][g]);                         \
            acc[1][g] = MFMA16(ah1, CL[g], acc[1][g]);                         \
            acc[1][g] = MFMA16(al1, CH[g], acc[1][g]);                         \
        }                                                                      \
    }

__global__ __launch_bounds__(512) void lstm_mfma(
    const float* __restrict__ emb, const float* __restrict__ add_info,
    const short* __restrict__ wB, const float* __restrict__ wadd,
    const float* __restrict__ bsum, const float* __restrict__ hx0,
    const float* __restrict__ cx0, float* __restrict__ hbuf)
{
    __shared__ short aP[12288];
    __shared__ float Sadd[2][32][2];
    const int tid = threadIdx.x;
    const int w  = tid >> 6;
    const int l  = tid & 63;
    const int li = l & 15;
    const int lk = l >> 4;
    const int R0 = blockIdx.x * 32;

    {
        int row = tid >> 4, j0 = (tid & 15) * 8;
        const float* hp = hx0 + (size_t)(R0 + row)*128 + j0;
        float4 h0 = *(const float4*)hp;
        float4 h1 = *(const float4*)(hp + 4);
        float v[8] = {h0.x,h0.y,h0.z,h0.w,h1.x,h1.y,h1.z,h1.w};
        short8v hi, lo;
#pragma unroll
        for (int e = 0; e < 8; ++e) {
            unsigned short hs = f2bf(v[e]);
            hi[e] = (short)hs;
            lo[e] = (short)f2bf(v[e] - bf2f(hs));
        }
        int mt = row >> 4, ln = (row & 15) + 16*((j0 >> 3) & 3), ki = j0 >> 5;
        *(short8v*)&aP[AIDX(0,ki,mt,ln)] = hi;
        *(short8v*)&aP[AIDX(1,ki,mt,ln)] = lo;
    }
    {
        int row = tid >> 4, d0 = (tid & 15)*4;
        int R = R0 + row, g = R/10, p = R - 10*g;
        float4 f = *(const float4*)&emb[((size_t)(g*TT + 0)*PP + p)*64 + d0];
        int k0 = 128 + d0;
        int mt = row>>4, ln = (row&15) + 16*((k0>>3)&3), ki = k0>>5, e0 = k0&7;
        float v[4] = {f.x,f.y,f.z,f.w};
        short4v hi, lo;
#pragma unroll
        for (int e = 0; e < 4; ++e) {
            unsigned short hs = f2bf(v[e]);
            hi[e] = (short)hs;
            lo[e] = (short)f2bf(v[e] - bf2f(hs));
        }
        *(short4v*)&aP[AIDX(0,ki,mt,ln)+e0] = hi;
        *(short4v*)&aP[AIDX(1,ki,mt,ln)+e0] = lo;
    }
    if (tid < 64) {
        int row = tid >> 1, cc = tid & 1;
        int R = R0 + row, g = R/10, p = R - 10*g;
        Sadd[0][row][cc] = add_info[((size_t)(g*MM + 0)*PP + p)*2 + cc];
    }
    float c[2][4];
#pragma unroll
    for (int mt = 0; mt < 2; ++mt)
#pragma unroll
        for (int r = 0; r < 4; ++r) {
            int row = mt*16 + lk*4 + r;
            c[mt][r] = cx0[(size_t)(R0+row)*128 + 16*w + li];
        }

    short8v b0h[4], b0l[4], b1h[4], b1l[4], b2h[4], b2l[4];
    LOADB(0, 0, b0h, b0l)
    LOADB(0, 1, b1h, b1l)
    __syncthreads();

    for (int t = 0; t < TT; ++t) {
        const int tn = (t < TT-1) ? t+1 : t;
        float4 fnext;
        {
            int row = tid >> 4, d0 = (tid & 15)*4;
            int R = R0 + row, g = R/10, p = R - 10*g;
            fnext = *(const float4*)&emb[((size_t)(g*TT + tn)*PP + p)*64 + d0];
        }
        float adn0 = 0.f;
        if (tid < 64) {
            int rw = tid >> 1, cc = tid & 1;
            int R2 = R0 + rw, g2 = R2/10, p2 = R2 - 10*g2;
            adn0 = add_info[((size_t)(g2*MM + tn/MM)*PP + p2)*2 + cc];
        }
        float wa0[4], wa1[4];
#pragma unroll
        for (int g = 0; g < 4; ++g) {
            wa0[g] = wadd[(size_t)(t*2+0)*512 + 128*g + 16*w + li];
            wa1[g] = wadd[(size_t)(t*2+1)*512 + 128*g + 16*w + li];
        }

        f32x4 acc[2][4];
#pragma unroll
        for (int g = 0; g < 4; ++g) {
            float bs = bsum[t*512 + 128*g + 16*w + li];
            acc[0][g] = (f32x4){bs,bs,bs,bs};
            acc[1][g] = (f32x4){bs,bs,bs,bs};
        }

        KI_STEP(0, b0h, b0l, t,  2, b2h, b2l)
        KI_STEP(1, b1h, b1l, t,  3, b0h, b0l)
        KI_STEP(2, b2h, b2l, t,  4, b1h, b1l)
        KI_STEP(3, b0h, b0l, t,  5, b2h, b2l)
        KI_STEP(4, b1h, b1l, tn, 0, b0h, b0l)
        KI_STEP(5, b2h, b2l, tn, 1, b1h, b1l)
        __syncthreads();

        const int sb = t & 1;
        const int j  = 16*w + li;
        const int jsh = 16*((j >> 3) & 3);
        const int jki = j >> 5;
        const int je  = j & 7;
#pragma unroll
        for (int mt = 0; mt < 2; ++mt) {
#pragma unroll
            for (int r = 0; r < 4; ++r) {
                int row = mt*16 + lk*4 + r;
                float ad0 = Sadd[sb][row][0], ad1 = Sadd[sb][row][1];
                float v0 = acc[mt][0][r] + ad0*wa0[0] + ad1*wa1[0];
                float v1 = acc[mt][1][r] + ad0*wa0[1] + ad1*wa1[1];
                float v2 = acc[mt][2][r] + ad0*wa0[2] + ad1*wa1[2];
                float v3 = acc[mt][3][r] + ad0*wa0[3] + ad1*wa1[3];
                float iv = sigm(v0);
                float fv = sigm(v1);
                float gv = tanh_fast(v2);
                float ov = sigm(v3);
                float cn = fv*c[mt][r] + iv*gv;
                c[mt][r] = cn;
                float hv = ov*tanh_fast(cn);
                unsigned short hs = f2bf(hv);
                int ln = (row & 15) + jsh;
                aP[AIDX(0, jki, mt, ln) + je] = (short)hs;
                aP[AIDX(1, jki, mt, ln) + je] = (short)f2bf(hv - bf2f(hs));
                if (t == TT-1) hbuf[(size_t)(R0+row)*128 + j] = hv;
            }
        }
        if (t < TT-1) {
            int row = tid >> 4, d0 = (tid & 15)*4;
            int k0 = 128 + d0;
            int mt = row>>4, ln = (row&15) + 16*((k0>>3)&3), ki = k0>>5, e0 = k0&7;
            float v[4] = {fnext.x, fnext.y, fnext.z, fnext.w};
            short4v hi, lo;
#pragma unroll
            for (int e = 0; e < 4; ++e) {
                unsigned short hs = f2bf(v[e]);
                hi[e] = (short)hs;
                lo[e] = (short)f2bf(v[e] - bf2f(hs));
            }
            *(short4v*)&aP[AIDX(0,ki,mt,ln)+e0] = hi;
            *(short4v*)&aP[AIDX(1,ki,mt,ln)+e0] = lo;
            if (tid < 64) {
                int rw = tid >> 1, cc = tid & 1;
                Sadd[sb^1][rw][cc] = adn0;
            }
        }
        __syncthreads();
    }
}

// ---------------------------------------------------------------------------
// Final projection: out = h_last @ Wf + bf
// ---------------------------------------------------------------------------
__global__ __launch_bounds__(256) void final_proj(
    const float* __restrict__ hbuf, const float* __restrict__ Wf,
    const float* __restrict__ bf, float* __restrict__ out)
{
    __shared__ float wl[128*32];
    __shared__ float hl[64][128];
    const int tid = threadIdx.x;
    const int row0 = blockIdx.x * 64;
    for (int i = tid; i < 4096; i += 256) wl[i] = Wf[i];
    for (int i = tid; i < 8192; i += 256) hl[i>>7][i&127] = hbuf[row0*128 + i];
    __syncthreads();
    const int e  = tid & 31;
    const int rg = tid >> 5;
    float b = bf[e];
    float acc[8];
#pragma unroll
    for (int r=0;r<8;++r) acc[r] = b;
    for (int k = 0; k < 128; ++k) {
        float ww = wl[k*32 + e];
#pragma unroll
        for (int r=0;r<8;++r) acc[r] += hl[rg*8+r][k]*ww;
    }
#pragma unroll
    for (int r=0;r<8;++r) out[(row0 + rg*8 + r)*32 + e] = acc[r];
}

// ---------------------------------------------------------------------------
extern "C" void kernel_launch(void* const* d_in, const int* in_sizes, int n_in,
                              void* d_out, int out_size, void* d_ws, size_t ws_size,
                              hipStream_t stream)
{
    const float* x0       = (const float*)d_in[0];
    const float* add_info = (const float*)d_in[1];
    const float* Wb_pos   = (const float*)d_in[2];
    const float* bb_pos   = (const float*)d_in[3];
    const float* Wb_neg   = (const float*)d_in[4];
    const float* bb_neg   = (const float*)d_in[5];
    const float* Wd_pos   = (const float*)d_in[6];
    const float* bd_pos   = (const float*)d_in[7];
    const float* Wd_neg   = (const float*)d_in[8];
    const float* bd_neg   = (const float*)d_in[9];
    const float* W_ih     = (const float*)d_in[10];
    const float* W_hh     = (const float*)d_in[11];
    const float* b_ih     = (const float*)d_in[12];
    const float* b_hh     = (const float*)d_in[13];
    const float* hx0      = (const float*)d_in[14];
    const float* cx0      = (const float*)d_in[15];
    const float* Wf       = (const float*)d_in[16];
    const float* bf       = (const float*)d_in[17];
    const int*   pos_src  = (const int*)d_in[18];
    const int*   pos_dst  = (const int*)d_in[19];
    const int*   neg_src  = (const int*)d_in[20];
    const int*   neg_dst  = (const int*)d_in[21];

    float* ws    = (float*)d_ws;
    float* emb   = ws;                        // 8,192,000 f32
    float* hbuf  = emb   + 8192000;           //   655,360 f32
    float* bsumw = hbuf  + 655360;            //    12,800 f32
    float* waddw = bsumw + 12800;             //    25,600 f32
    short* wBw   = (short*)(waddw + 25600);   // 4,915,200 shorts
    short* wGw   = wBw + 4915200;             //    73,728 shorts (~45.6 MiB total)

    hipLaunchKernelGGL(prep_kernel, dim3(2048), dim3(256), 0, stream,
                       W_ih, W_hh, b_ih, b_hh, Wb_pos, Wb_neg, Wd_pos, Wd_neg,
                       wBw, waddw, bsumw, wGw);
    hipLaunchKernelGGL(graph_kernel, dim3(NGRAPH/8), dim3(256), 0, stream,
                       x0, bb_pos, bb_neg, bd_pos, bd_neg, wGw,
                       pos_src, pos_dst, neg_src, neg_dst, emb);
    hipLaunchKernelGGL(lstm_mfma, dim3(160), dim3(512), 0, stream,
                       emb, add_info, wBw, waddw, bsumw, hx0, cx0, hbuf);
    hipLaunchKernelGGL(final_proj, dim3(80), dim3(256), 0, stream,
                       hbuf, Wf, bf, (float*)d_out);
}